// Round 19
// baseline (452.925 us; speedup 1.0000x reference)
//
#include <hip/hip_runtime.h>
#include <hip/hip_bf16.h>
#include <type_traits>

#define DIM 1024
#define HID 4096
#define NH 16
#define HD 64
#define BB 4
#define SS 2048
#define NROW (BB*SS)   // 8192

typedef __attribute__((ext_vector_type(8))) short short8;
typedef __attribute__((ext_vector_type(4))) short short4v;
typedef __attribute__((ext_vector_type(4))) float f32x4;

__device__ __forceinline__ void gload16(const void* src, void* lds) {
  __builtin_amdgcn_global_load_lds(
      (const __attribute__((address_space(1))) unsigned int*)src,
      (__attribute__((address_space(3))) unsigned int*)lds, 16, 0, 0);
}
__device__ __forceinline__ short f2b(float f) {
  return __builtin_bit_cast(short, __float2bfloat16(f));
}
__device__ __forceinline__ float b2f(short s) {
  return __uint_as_float(((unsigned)(unsigned short)s) << 16);
}

// ---------------- LayerNorm: one row (1024) per 256-thread block ----------------
// fp32 in, bf16 out.
__global__ __launch_bounds__(256) void ln_k(const float* __restrict__ x,
                                            const float* __restrict__ g,
                                            const float* __restrict__ bta,
                                            short* __restrict__ out) {
  int row = blockIdx.x;
  int t = threadIdx.x;
  int lane = t & 63, wid = t >> 6;
  float4 v = *(const float4*)(x + (size_t)row*DIM + t*4);
  float f[4] = {v.x, v.y, v.z, v.w};
  float s1 = 0.f, s2 = 0.f;
#pragma unroll
  for (int j = 0; j < 4; j++) { s1 += f[j]; s2 += f[j]*f[j]; }
#pragma unroll
  for (int off = 32; off > 0; off >>= 1) { s1 += __shfl_xor(s1, off); s2 += __shfl_xor(s2, off); }
  __shared__ float red[8];
  if (lane == 0) { red[wid] = s1; red[4+wid] = s2; }
  __syncthreads();
  s1 = red[0]+red[1]+red[2]+red[3];
  s2 = red[4]+red[5]+red[6]+red[7];
  float mu = s1 * (1.0f/DIM);
  float var = s2 * (1.0f/DIM) - mu*mu;
  float rs = rsqrtf(var + 1e-5f);
  float4 gv = *(const float4*)(g + t*4);
  float4 bv = *(const float4*)(bta + t*4);
  short4v o;
  o[0] = f2b((f[0]-mu)*rs*gv.x + bv.x);
  o[1] = f2b((f[1]-mu)*rs*gv.y + bv.y);
  o[2] = f2b((f[2]-mu)*rs*gv.z + bv.z);
  o[3] = f2b((f[3]-mu)*rs*gv.w + bv.w);
  *(short4v*)(out + (size_t)row*DIM + t*4) = o;
}

// ------------- fp32 -> bf16 2D transpose (R,C multiples of 64) -------------
__global__ __launch_bounds__(256) void transp_f2b(const float* __restrict__ in, short* __restrict__ out,
                                                  int R, int C) {
  __shared__ __align__(16) short tile[64][72];
  int r0 = blockIdx.x*64, c0 = blockIdx.y*64;
  int t = threadIdx.x;
  int cr = t >> 4;           // 0..15
  int cc4 = (t & 15) * 4;    // 0..60
#pragma unroll
  for (int i = 0; i < 4; i++) {
    float4 v = *(const float4*)(in + (size_t)(r0 + cr + i*16)*C + c0 + cc4);
    tile[cr + i*16][cc4 + 0] = f2b(v.x);
    tile[cr + i*16][cc4 + 1] = f2b(v.y);
    tile[cr + i*16][cc4 + 2] = f2b(v.z);
    tile[cr + i*16][cc4 + 3] = f2b(v.w);
  }
  __syncthreads();
  int rr = t >> 3, cc = (t & 7) * 8;
#pragma unroll
  for (int i = 0; i < 2; i++) {
    int oc = rr + i*32;
    short8 v;
#pragma unroll
    for (int j = 0; j < 8; j++) v[j] = tile[cc + j][oc];
    *(short8*)(out + (size_t)(c0 + oc)*R + r0 + cc) = v;
  }
}

// ---------------- V transpose: qkv v-cols [b,s,h,d] -> vt [b,h,d,s] ----------------
__global__ __launch_bounds__(256) void vtrans(const short* __restrict__ qkv, short* __restrict__ vt) {
  __shared__ __align__(16) short tile[64][72];
  int s0 = blockIdx.x*64;
  int z = blockIdx.y; int b = z >> 4, h = z & 15;
  int t = threadIdx.x;
  int rr = t >> 3, cc = (t & 7) * 8;
#pragma unroll
  for (int i = 0; i < 2; i++) {
    short8 v = *(const short8*)(qkv + (size_t)(b*SS + s0 + rr + i*32)*(3*DIM) + 2*DIM + h*HD + cc);
    *(short8*)&tile[rr + i*32][cc] = v;
  }
  __syncthreads();
#pragma unroll
  for (int i = 0; i < 2; i++) {
    int d = rr + i*32;
    short8 v;
#pragma unroll
    for (int j = 0; j < 8; j++) v[j] = tile[cc + j][d];
    *(short8*)(vt + ((size_t)z*HD + d)*SS + s0 + cc) = v;
  }
}

// ---------------- GEMM: C[M,N] = A[M,K] * Bt[N,K]^T  (producer-consumer waves) ----------------
// 640 threads: waves 0-7 compute (2M x 4N, 64x32 output/wave, r16-verified frags/swizzle),
// waves 8-9 are LOADERS (wave8 = A-tile, wave9 = B-tile; 16 gload16 each per K-step).
// Compute waves issue NO vmem in the loop -> their __syncthreads has no vmcnt drain;
// the HBM/L2 latency is paid by loader waves WHILE compute waves crunch MFMAs.
// Double-buffered [2][128][64] bf16 LDS (64 KB) -> 2 blocks/CU. XOR swizzle per rule #21.
// Barrier counts match across roles: 1 prologue + nt each.
// EPI: 0 = none, 1 = relu, 3 = add fp32 residual.  CT: short (bf16 out) or float (fp32 out).
template<int EPI, typename CT>
__global__ __launch_bounds__(640) void gemm_bt(const short* __restrict__ A, int lda,
                                               const short* __restrict__ Bt, int ldb,
                                               CT* C, int ldc,
                                               const float* Res, int ldr,
                                               int K) {
  __shared__ __align__(16) short ldsA[2][128*64];
  __shared__ __align__(16) short ldsB[2][128*64];
  int t = threadIdx.x, lane = t & 63, wid = t >> 6;
  int bm = blockIdx.x*128, bn = blockIdx.y*128;
  const int nt = K >> 6;

  if (wid >= 8) {
    // ---- loader role: wave 8 stages A, wave 9 stages B ----
    const short* base = (wid == 8) ? (A + (size_t)bm*lda) : (Bt + (size_t)bn*ldb);
    const int ldx = (wid == 8) ? lda : ldb;
    short* d0 = (wid == 8) ? ldsA[0] : ldsB[0];
    short* d1 = (wid == 8) ? ldsA[1] : ldsB[1];
    // issue j writes rows j*8 + (lane>>3); source col-slot pre-swizzled (row&7 == lane>>3)
    const int srcCol = (((lane & 7) ^ (lane >> 3)) * 8);
    const short* p = base + (size_t)(lane >> 3)*ldx + srcCol;
#pragma unroll
    for (int j = 0; j < 16; j++) gload16(p + (size_t)(j*8)*ldx, d0 + j*512);
    __syncthreads();                       // tile 0 staged (own vmcnt drained here)
    for (int tt = 0; tt < nt; tt++) {
      if (tt + 1 < nt) {
        const short* pn = p + (size_t)(tt + 1)*64;
        short* d = ((tt + 1) & 1) ? d1 : d0;
#pragma unroll
        for (int j = 0; j < 16; j++) gload16(pn + (size_t)(j*8)*ldx, d + j*512);
      }
      __syncthreads();                     // drain own loads; compute finishes buf[tt&1]
    }
    return;
  }

  // ---- compute role: 8 waves, 2M x 4N, 64x32 output per wave ----
  int wr = wid >> 2, wc = wid & 3;
  f32x4 z4 = {0.f, 0.f, 0.f, 0.f};
  f32x4 acc[4][2];
#pragma unroll
  for (int m = 0; m < 4; m++)
#pragma unroll
    for (int n = 0; n < 2; n++) acc[m][n] = z4;
  const int rowXor = (lane & 7) << 3;      // read-side col XOR (frag row&7 == lane&7)
  __syncthreads();                         // matches loader prologue barrier
  for (int tt = 0; tt < nt; tt++) {
    const short* bA = ldsA[tt & 1];
    const short* bB = ldsB[tt & 1];
    short8 af[4][2], bfr[2][2];
#pragma unroll
    for (int m = 0; m < 4; m++) {
      int row = wr*64 + m*16 + (lane & 15);
#pragma unroll
      for (int kk = 0; kk < 2; kk++)
        af[m][kk] = *(const short8*)&bA[row*64 + ((kk*32 + (lane >> 4)*8) ^ rowXor)];
    }
#pragma unroll
    for (int n = 0; n < 2; n++) {
      int row = wc*32 + n*16 + (lane & 15);
#pragma unroll
      for (int kk = 0; kk < 2; kk++)
        bfr[n][kk] = *(const short8*)&bB[row*64 + ((kk*32 + (lane >> 4)*8) ^ rowXor)];
    }
    __builtin_amdgcn_s_setprio(1);
#pragma unroll
    for (int m = 0; m < 4; m++)
#pragma unroll
      for (int n = 0; n < 2; n++)
#pragma unroll
        for (int kk = 0; kk < 2; kk++)
          acc[m][n] = __builtin_amdgcn_mfma_f32_16x16x32_bf16(af[m][kk], bfr[n][kk], acc[m][n], 0, 0, 0);
    __builtin_amdgcn_s_setprio(0);
    __syncthreads();                       // no vmem outstanding -> cheap for compute waves
  }
#pragma unroll
  for (int m = 0; m < 4; m++) {
    int r0 = bm + wr*64 + m*16 + ((lane >> 4) << 2);
#pragma unroll
    for (int n = 0; n < 2; n++) {
      int c = bn + wc*32 + n*16 + (lane & 15);
#pragma unroll
      for (int r = 0; r < 4; r++) {
        float v = acc[m][n][r];
        if constexpr (EPI == 1) v = fmaxf(v, 0.0f);
        if constexpr (EPI == 3) v += Res[(size_t)(r0 + r)*ldr + c];
        if constexpr (std::is_same<CT, float>::value)
          C[(size_t)(r0 + r)*ldc + c] = v;
        else
          C[(size_t)(r0 + r)*ldc + c] = f2b(v);
      }
    }
  }
}

// ---------------- causal flash attention (MFMA, QBLK=128, 8 waves, XCD-clustered) ----------------
// 512 threads = 8 waves; wave w owns rows q0 + w*16 .. +15 (ONE frag/wave).
// half = wid>>2: wave active iff it <= 2*qi+half; diagonal-masked iff equal.
__global__ __launch_bounds__(512) void attn_k(short* qkv, const short* __restrict__ vt) {
  __shared__ __align__(16) short ldsK[2][64*64];
  __shared__ __align__(16) short ldsV[2][64*64];
  __shared__ __align__(16) short ldsP[8][16*64];
  int t = threadIdx.x, lane = t & 63, wid = t >> 6;
  int wgid = blockIdx.x;
  int xcd = wgid & 7, idx = wgid >> 3;
  int z  = xcd*8 + (idx & 7);
  int qi = 15 - (idx >> 3);            // longest-first within each XCD
  int q0 = qi*128;
  int b = z >> 4, h = z & 15;
  const int ld = 3*DIM;
  const float SCALE2 = 0.125f * 1.44269504f;   // 1/sqrt(HD) * log2(e)
  const float THR2   = 8.0f * 1.44269504f;     // defer-max threshold (exp2 domain)
  const int half = wid >> 2;
  const int myq = q0 + wid*16;                 // wave's first q-row
  short8 qf[2];
  {
    const short* qp = qkv + (size_t)(b*SS + myq + (lane & 15))*ld + h*HD + (lane >> 4)*8;
    qf[0] = *(const short8*)qp;
    qf[1] = *(const short8*)(qp + 32);
  }
  f32x4 z4 = {0.f, 0.f, 0.f, 0.f};
  f32x4 accO[4];
#pragma unroll
  for (int n = 0; n < 4; n++) accO[n] = z4;
  float m_r[4], lp[4];   // running max (exp2 domain), per-lane PARTIAL l
#pragma unroll
  for (int r = 0; r < 4; r++) { m_r[r] = -1e30f; lp[r] = 0.f; }
  const int srcCol = (((lane & 7) ^ ((lane >> 3) & 7)) * 8);  // pre-swizzled staging col
  const int rowXor = (lane & 7) << 3;                         // read-side col XOR
  int ntiles = 2*qi + 2;

  // 512 threads x 16B = full 64x64 bf16 tile in ONE issue per matrix.
  auto STAGE = [&](int it, int bsel) {
    int kv0 = it*64;
    const short* sk = qkv + (size_t)(b*SS + kv0 + (t >> 3))*ld + DIM + h*HD + srcCol;
    gload16(sk, &ldsK[bsel][wid*512]);
    const short* sv = vt + ((size_t)z*HD + (t >> 3))*SS + kv0 + srcCol;
    gload16(sv, &ldsV[bsel][wid*512]);
  };

  STAGE(0, 0);
  __syncthreads();
  for (int it = 0; it < ntiles; ++it) {
    int cur = it & 1;
    if (it + 1 < ntiles) STAGE(it + 1, cur ^ 1);
    int kv0 = it*64;
    if (it <= 2*qi + half) {           // wave-uniform activity predicate
      f32x4 sacc[4];
#pragma unroll
      for (int n = 0; n < 4; n++) sacc[n] = z4;
      __builtin_amdgcn_s_setprio(1);
#pragma unroll
      for (int n = 0; n < 4; n++) {
#pragma unroll
        for (int kk = 0; kk < 2; kk++) {
          int colK = (kk*32 + (lane >> 4)*8) ^ rowXor;
          short8 kb = *(const short8*)&ldsK[cur][(n*16 + (lane & 15))*64 + colK];
          sacc[n] = __builtin_amdgcn_mfma_f32_16x16x32_bf16(qf[kk], kb, sacc[n], 0, 0, 0);
        }
      }
      __builtin_amdgcn_s_setprio(0);
      if (it == 2*qi + half) {         // diagonal tile: mask raw scores
#pragma unroll
        for (int n = 0; n < 4; n++) {
          int kg = kv0 + n*16 + (lane & 15);
#pragma unroll
          for (int r = 0; r < 4; r++) {
            int qg = myq + ((lane >> 4) << 2) + r;
            sacc[n][r] = (kg <= qg) ? sacc[n][r] : -1e30f;
          }
        }
      }
      float mxs[4];
      float dmax = -1e30f;
#pragma unroll
      for (int r = 0; r < 4; r++) {
        float mx = fmaxf(fmaxf(sacc[0][r], sacc[1][r]), fmaxf(sacc[2][r], sacc[3][r]));
#pragma unroll
        for (int off = 1; off < 16; off <<= 1) mx = fmaxf(mx, __shfl_xor(mx, off));
        mxs[r] = mx * SCALE2;                       // scale once per row
        dmax = fmaxf(dmax, mxs[r] - m_r[r]);
      }
      if (__any(dmax > THR2)) {                     // T13: rescale only when needed
#pragma unroll
        for (int r = 0; r < 4; r++) {
          float mn = fmaxf(m_r[r], mxs[r]);
          float al = exp2f(m_r[r] - mn);
          m_r[r] = mn;
          lp[r] *= al;
#pragma unroll
          for (int n = 0; n < 4; n++) accO[n][r] *= al;
        }
      }
#pragma unroll
      for (int r = 0; r < 4; r++) {
        float mn = m_r[r];
        float rs = 0.f;
#pragma unroll
        for (int n = 0; n < 4; n++) {
          float p = exp2f(fmaf(sacc[n][r], SCALE2, -mn));
          sacc[n][r] = p;
          rs += p;
        }
        lp[r] += rs;                                // per-lane partial; reduce at end
      }
      // P -> per-wave LDS (A-operand layout, XOR-swizzled; same-wave r/w: no barrier)
#pragma unroll
      for (int n = 0; n < 4; n++)
#pragma unroll
        for (int r = 0; r < 4; r++) {
          int prow = ((lane >> 4) << 2) + r;
          int pcol = (n*16 + (lane & 15)) ^ ((prow & 7) << 3);
          ldsP[wid][prow*64 + pcol] = f2b(sacc[n][r]);
        }
      __builtin_amdgcn_s_setprio(1);
#pragma unroll
      for (int nn = 0; nn < 4; nn++) {
#pragma unroll
        for (int kk = 0; kk < 2; kk++) {
          int colP = (kk*32 + (lane >> 4)*8) ^ rowXor;
          short8 vb  = *(const short8*)&ldsV[cur][(nn*16 + (lane & 15))*64 + colP];
          short8 pfr = *(const short8*)&ldsP[wid][(lane & 15)*64 + colP];
          accO[nn] = __builtin_amdgcn_mfma_f32_16x16x32_bf16(pfr, vb, accO[nn], 0, 0, 0);
        }
      }
      __builtin_amdgcn_s_setprio(0);
    }
    __syncthreads();   // next tile staged; all waves done with cur bufs
  }
  // epilogue: finish deferred l row-reduction, divide, store
  {
    float rl[4];
#pragma unroll
    for (int r = 0; r < 4; r++) {
      float l = lp[r];
#pragma unroll
      for (int off = 1; off < 16; off <<= 1) l += __shfl_xor(l, off);
      rl[r] = 1.0f / l;
    }
#pragma unroll
    for (int nn = 0; nn < 4; nn++) {
#pragma unroll
      for (int r = 0; r < 4; r++) {
        int qg = myq + ((lane >> 4) << 2) + r;
        float ov = accO[nn][r] * rl[r];
        qkv[(size_t)(b*SS + qg)*ld + 2*DIM + h*HD + nn*16 + (lane & 15)] = f2b(ov);
      }
    }
  }
}

extern "C" void kernel_launch(void* const* d_in, const int* in_sizes, int n_in,
                              void* d_out, int out_size, void* d_ws, size_t ws_size,
                              hipStream_t stream) {
  (void)in_sizes; (void)n_in; (void)out_size; (void)ws_size;
  const float* x    = (const float*)d_in[0];
  // d_in[1] = mask: causal with -1e9 fill -> applied analytically, ignored
  const float* wq   = (const float*)d_in[2];
  const float* wk   = (const float*)d_in[3];
  const float* wv   = (const float*)d_in[4];
  const float* wo   = (const float*)d_in[5];
  const float* w1   = (const float*)d_in[6];
  const float* w2   = (const float*)d_in[7];
  const float* ln1w = (const float*)d_in[8];
  const float* ln1b = (const float*)d_in[9];
  const float* ln2w = (const float*)d_in[10];
  const float* ln2b = (const float*)d_in[11];
  float* out = (float*)d_out;   // fp32 output (verified r8)

  short* ws = (short*)d_ws;
  size_t o = 0;
  short* wqkvT = ws + o; o += (size_t)3*DIM*DIM;   // [3072][1024] bf16
  short* woT   = ws + o; o += (size_t)DIM*DIM;     // [1024][1024]
  short* w1T   = ws + o; o += (size_t)HID*DIM;     // [4096][1024]
  short* w2T   = ws + o; o += (size_t)DIM*HID;     // [1024][4096]
  short* xn    = ws + o; o += (size_t)NROW*DIM;    // LN1 out -> LN2 out (disjoint lifetimes)
  short* qkv   = ws + o; o += (size_t)NROW*3*DIM;  // q|k|v cols; v cols overwritten by attn out
  short* ff1   = ws + o; o += (size_t)NROW*HID;    // relu(hn@w1); front 16MB doubles as vt earlier
  short* vtb   = ff1;                              // [b,h,d,s] — lifetime disjoint from ff1

  dim3 B256(256), B512(512), B640(640);
  // weight transposes (fp32 -> bf16, B^T convention for gemm_bt)
  transp_f2b<<<dim3(16,16), B256, 0, stream>>>(wq, wqkvT,             DIM, DIM);
  transp_f2b<<<dim3(16,16), B256, 0, stream>>>(wk, wqkvT + DIM*DIM,   DIM, DIM);
  transp_f2b<<<dim3(16,16), B256, 0, stream>>>(wv, wqkvT + 2*DIM*DIM, DIM, DIM);
  transp_f2b<<<dim3(16,16), B256, 0, stream>>>(wo, woT, DIM, DIM);
  transp_f2b<<<dim3(16,64), B256, 0, stream>>>(w1, w1T, DIM, HID);
  transp_f2b<<<dim3(64,16), B256, 0, stream>>>(w2, w2T, HID, DIM);
  // xn = LN1(x)   (fp32 in, bf16 out)
  ln_k<<<NROW, B256, 0, stream>>>(x, ln1w, ln1b, xn);
  // qkv = xn @ [wq|wk|wv]   (bf16 out)
  gemm_bt<0, short><<<dim3(NROW/128, 3*DIM/128), B640, 0, stream>>>(xn, DIM, wqkvT, DIM, qkv, 3*DIM, nullptr, 0, DIM);
  // vt = transpose(v) per (b,h)
  vtrans<<<dim3(SS/64, BB*NH), B256, 0, stream>>>(qkv, vtb);
  // attention (writes into qkv v-columns, bf16)
  attn_k<<<dim3(1024), B512, 0, stream>>>(qkv, vtb);
  // h = x + attn @ wo   (fp32 h in d_out)
  gemm_bt<3, float><<<dim3(NROW/128, DIM/128), B640, 0, stream>>>(qkv + 2*DIM, 3*DIM, woT, DIM, out, DIM, x, DIM, DIM);
  // hn = LN2(h) (fp32 in, bf16 out into xn)
  ln_k<<<NROW, B256, 0, stream>>>(out, ln2w, ln2b, xn);
  // ff1 = relu(hn @ w1)  (bf16 out)
  gemm_bt<1, short><<<dim3(NROW/128, HID/128), B640, 0, stream>>>(xn, DIM, w1T, DIM, ff1, HID, nullptr, 0, DIM);
  // out = h + ff1 @ w2   (fp32 in-place residual: each element read+written by its own thread)
  gemm_bt<3, float><<<dim3(NROW/128, DIM/128), B640, 0, stream>>>(ff1, HID, w2T, HID, out, DIM, out, DIM, HID);
}

// Round 20
// 388.298 us; speedup vs baseline: 1.1664x; 1.1664x over previous
//
#include <hip/hip_runtime.h>
#include <hip/hip_bf16.h>
#include <type_traits>

#define DIM 1024
#define HID 4096
#define NH 16
#define HD 64
#define BB 4
#define SS 2048
#define NROW (BB*SS)   // 8192

typedef __attribute__((ext_vector_type(8))) short short8;
typedef __attribute__((ext_vector_type(4))) short short4v;
typedef __attribute__((ext_vector_type(4))) float f32x4;

__device__ __forceinline__ void gload16(const void* src, void* lds) {
  __builtin_amdgcn_global_load_lds(
      (const __attribute__((address_space(1))) unsigned int*)src,
      (__attribute__((address_space(3))) unsigned int*)lds, 16, 0, 0);
}
__device__ __forceinline__ short f2b(float f) {
  return __builtin_bit_cast(short, __float2bfloat16(f));
}
__device__ __forceinline__ float b2f(short s) {
  return __uint_as_float(((unsigned)(unsigned short)s) << 16);
}

// ---------------- LayerNorm: one row (1024) per 256-thread block ----------------
// fp32 in, bf16 out.
__global__ __launch_bounds__(256) void ln_k(const float* __restrict__ x,
                                            const float* __restrict__ g,
                                            const float* __restrict__ bta,
                                            short* __restrict__ out) {
  int row = blockIdx.x;
  int t = threadIdx.x;
  int lane = t & 63, wid = t >> 6;
  float4 v = *(const float4*)(x + (size_t)row*DIM + t*4);
  float f[4] = {v.x, v.y, v.z, v.w};
  float s1 = 0.f, s2 = 0.f;
#pragma unroll
  for (int j = 0; j < 4; j++) { s1 += f[j]; s2 += f[j]*f[j]; }
#pragma unroll
  for (int off = 32; off > 0; off >>= 1) { s1 += __shfl_xor(s1, off); s2 += __shfl_xor(s2, off); }
  __shared__ float red[8];
  if (lane == 0) { red[wid] = s1; red[4+wid] = s2; }
  __syncthreads();
  s1 = red[0]+red[1]+red[2]+red[3];
  s2 = red[4]+red[5]+red[6]+red[7];
  float mu = s1 * (1.0f/DIM);
  float var = s2 * (1.0f/DIM) - mu*mu;
  float rs = rsqrtf(var + 1e-5f);
  float4 gv = *(const float4*)(g + t*4);
  float4 bv = *(const float4*)(bta + t*4);
  short4v o;
  o[0] = f2b((f[0]-mu)*rs*gv.x + bv.x);
  o[1] = f2b((f[1]-mu)*rs*gv.y + bv.y);
  o[2] = f2b((f[2]-mu)*rs*gv.z + bv.z);
  o[3] = f2b((f[3]-mu)*rs*gv.w + bv.w);
  *(short4v*)(out + (size_t)row*DIM + t*4) = o;
}

// ------------- fp32 -> bf16 2D transpose (R,C multiples of 64) -------------
__global__ __launch_bounds__(256) void transp_f2b(const float* __restrict__ in, short* __restrict__ out,
                                                  int R, int C) {
  __shared__ __align__(16) short tile[64][72];
  int r0 = blockIdx.x*64, c0 = blockIdx.y*64;
  int t = threadIdx.x;
  int cr = t >> 4;           // 0..15
  int cc4 = (t & 15) * 4;    // 0..60
#pragma unroll
  for (int i = 0; i < 4; i++) {
    float4 v = *(const float4*)(in + (size_t)(r0 + cr + i*16)*C + c0 + cc4);
    tile[cr + i*16][cc4 + 0] = f2b(v.x);
    tile[cr + i*16][cc4 + 1] = f2b(v.y);
    tile[cr + i*16][cc4 + 2] = f2b(v.z);
    tile[cr + i*16][cc4 + 3] = f2b(v.w);
  }
  __syncthreads();
  int rr = t >> 3, cc = (t & 7) * 8;
#pragma unroll
  for (int i = 0; i < 2; i++) {
    int oc = rr + i*32;
    short8 v;
#pragma unroll
    for (int j = 0; j < 8; j++) v[j] = tile[cc + j][oc];
    *(short8*)(out + (size_t)(c0 + oc)*R + r0 + cc) = v;
  }
}

// ------------- batched 1024x1024 fp32 -> bf16 transpose (4 matrices, one launch) -------------
__global__ __launch_bounds__(256) void transp_f2b4(const float* __restrict__ w0, const float* __restrict__ w1,
                                                   const float* __restrict__ w2, const float* __restrict__ w3,
                                                   short* __restrict__ o0, short* __restrict__ o1,
                                                   short* __restrict__ o2, short* __restrict__ o3) {
  __shared__ __align__(16) short tile[64][72];
  int zz = blockIdx.z;
  const float* in = (zz == 0) ? w0 : (zz == 1) ? w1 : (zz == 2) ? w2 : w3;
  short* out = (zz == 0) ? o0 : (zz == 1) ? o1 : (zz == 2) ? o2 : o3;
  const int R = DIM, C = DIM;
  int r0 = blockIdx.x*64, c0 = blockIdx.y*64;
  int t = threadIdx.x;
  int cr = t >> 4;
  int cc4 = (t & 15) * 4;
#pragma unroll
  for (int i = 0; i < 4; i++) {
    float4 v = *(const float4*)(in + (size_t)(r0 + cr + i*16)*C + c0 + cc4);
    tile[cr + i*16][cc4 + 0] = f2b(v.x);
    tile[cr + i*16][cc4 + 1] = f2b(v.y);
    tile[cr + i*16][cc4 + 2] = f2b(v.z);
    tile[cr + i*16][cc4 + 3] = f2b(v.w);
  }
  __syncthreads();
  int rr = t >> 3, cc = (t & 7) * 8;
#pragma unroll
  for (int i = 0; i < 2; i++) {
    int oc = rr + i*32;
    short8 v;
#pragma unroll
    for (int j = 0; j < 8; j++) v[j] = tile[cc + j][oc];
    *(short8*)(out + (size_t)(c0 + oc)*R + r0 + cc) = v;
  }
}

// ---------------- V transpose: qkv v-cols [b,s,h,d] -> vt [b,h,d,s] ----------------
__global__ __launch_bounds__(256) void vtrans(const short* __restrict__ qkv, short* __restrict__ vt) {
  __shared__ __align__(16) short tile[64][72];
  int s0 = blockIdx.x*64;
  int z = blockIdx.y; int b = z >> 4, h = z & 15;
  int t = threadIdx.x;
  int rr = t >> 3, cc = (t & 7) * 8;
#pragma unroll
  for (int i = 0; i < 2; i++) {
    short8 v = *(const short8*)(qkv + (size_t)(b*SS + s0 + rr + i*32)*(3*DIM) + 2*DIM + h*HD + cc);
    *(short8*)&tile[rr + i*32][cc] = v;
  }
  __syncthreads();
#pragma unroll
  for (int i = 0; i < 2; i++) {
    int d = rr + i*32;
    short8 v;
#pragma unroll
    for (int j = 0; j < 8; j++) v[j] = tile[cc + j][d];
    *(short8*)(vt + ((size_t)z*HD + d)*SS + s0 + cc) = v;
  }
}

// ---------------- GEMM: C[M,N] = A[M,K] * Bt[N,K]^T  (128² tile, BK=128, 8 waves) ----------------
// r18 measured-best version (394.6 µs total). 512 threads, 2Mx4N waves, 64x32/wave.
// BK=128: minimal barrier-drain events at zero occupancy cost (VGPR-capped 2 blocks/CU).
// [128][128] bf16 LDS rows (256B) -> 16-slot XOR swizzle (rule #21).
// EPI: 0 = none, 1 = relu, 3 = add fp32 residual.  CT: short (bf16 out) or float (fp32 out).
template<int EPI, typename CT>
__global__ __launch_bounds__(512) void gemm_bt(const short* __restrict__ A, int lda,
                                               const short* __restrict__ Bt, int ldb,
                                               CT* C, int ldc,
                                               const float* Res, int ldr,
                                               int K) {
  __shared__ __align__(16) short ldsA[128*128];   // 32 KB
  __shared__ __align__(16) short ldsB[128*128];   // 32 KB
  int t = threadIdx.x, lane = t & 63, wid = t >> 6;
  int bm = blockIdx.x*128, bn = blockIdx.y*128;
  int wr = wid >> 2, wc = wid & 3;     // 2M x 4N wave grid, 64x32 per wave
  f32x4 z4 = {0.f, 0.f, 0.f, 0.f};
  f32x4 acc[4][2];
#pragma unroll
  for (int m = 0; m < 4; m++)
#pragma unroll
    for (int n = 0; n < 2; n++) acc[m][n] = z4;
  const int srcCol = (((t & 15) ^ ((t >> 4) & 15)) * 8);
  const short* pa = A + (size_t)(bm + (t >> 4))*lda + srcCol;
  const short* pb = Bt + (size_t)(bn + (t >> 4))*ldb + srcCol;
  const int rdXor = (lane & 15) << 3;   // read-side col XOR (frag row&15 == lane&15)
  for (int k0 = 0; k0 < K; k0 += 128) {
#pragma unroll
    for (int i = 0; i < 4; i++) {
      gload16(pa + (size_t)(i*32)*lda, &ldsA[i*4096 + wid*512]);
      gload16(pb + (size_t)(i*32)*ldb, &ldsB[i*4096 + wid*512]);
    }
    pa += 128; pb += 128;
    __syncthreads();
#pragma unroll
    for (int kk = 0; kk < 4; kk++) {
      short8 af[4], bfr[2];
#pragma unroll
      for (int m = 0; m < 4; m++) {
        int row = wr*64 + m*16 + (lane & 15);
        af[m] = *(const short8*)&ldsA[row*128 + ((kk*32 + (lane >> 4)*8) ^ rdXor)];
      }
#pragma unroll
      for (int n = 0; n < 2; n++) {
        int row = wc*32 + n*16 + (lane & 15);
        bfr[n] = *(const short8*)&ldsB[row*128 + ((kk*32 + (lane >> 4)*8) ^ rdXor)];
      }
#pragma unroll
      for (int m = 0; m < 4; m++)
#pragma unroll
        for (int n = 0; n < 2; n++)
          acc[m][n] = __builtin_amdgcn_mfma_f32_16x16x32_bf16(af[m], bfr[n], acc[m][n], 0, 0, 0);
    }
    __syncthreads();
  }
#pragma unroll
  for (int m = 0; m < 4; m++) {
    int r0 = bm + wr*64 + m*16 + ((lane >> 4) << 2);
#pragma unroll
    for (int n = 0; n < 2; n++) {
      int c = bn + wc*32 + n*16 + (lane & 15);
#pragma unroll
      for (int r = 0; r < 4; r++) {
        float v = acc[m][n][r];
        if constexpr (EPI == 1) v = fmaxf(v, 0.0f);
        if constexpr (EPI == 3) v += Res[(size_t)(r0 + r)*ldr + c];
        if constexpr (std::is_same<CT, float>::value)
          C[(size_t)(r0 + r)*ldc + c] = v;
        else
          C[(size_t)(r0 + r)*ldc + c] = f2b(v);
      }
    }
  }
}

// ---------------- causal flash attention (MFMA, QBLK=128, 8 waves, XCD-clustered) ----------------
// 512 threads = 8 waves; wave w owns rows q0 + w*16 .. +15 (ONE frag/wave).
// half = wid>>2: wave active iff it <= 2*qi+half; diagonal-masked iff equal.
__global__ __launch_bounds__(512) void attn_k(short* qkv, const short* __restrict__ vt) {
  __shared__ __align__(16) short ldsK[2][64*64];
  __shared__ __align__(16) short ldsV[2][64*64];
  __shared__ __align__(16) short ldsP[8][16*64];
  int t = threadIdx.x, lane = t & 63, wid = t >> 6;
  int wgid = blockIdx.x;
  int xcd = wgid & 7, idx = wgid >> 3;
  int z  = xcd*8 + (idx & 7);
  int qi = 15 - (idx >> 3);            // longest-first within each XCD
  int q0 = qi*128;
  int b = z >> 4, h = z & 15;
  const int ld = 3*DIM;
  const float SCALE2 = 0.125f * 1.44269504f;   // 1/sqrt(HD) * log2(e)
  const float THR2   = 8.0f * 1.44269504f;     // defer-max threshold (exp2 domain)
  const int half = wid >> 2;
  const int myq = q0 + wid*16;                 // wave's first q-row
  short8 qf[2];
  {
    const short* qp = qkv + (size_t)(b*SS + myq + (lane & 15))*ld + h*HD + (lane >> 4)*8;
    qf[0] = *(const short8*)qp;
    qf[1] = *(const short8*)(qp + 32);
  }
  f32x4 z4 = {0.f, 0.f, 0.f, 0.f};
  f32x4 accO[4];
#pragma unroll
  for (int n = 0; n < 4; n++) accO[n] = z4;
  float m_r[4], lp[4];   // running max (exp2 domain), per-lane PARTIAL l
#pragma unroll
  for (int r = 0; r < 4; r++) { m_r[r] = -1e30f; lp[r] = 0.f; }
  const int srcCol = (((lane & 7) ^ ((lane >> 3) & 7)) * 8);  // pre-swizzled staging col
  const int rowXor = (lane & 7) << 3;                         // read-side col XOR
  int ntiles = 2*qi + 2;

  // 512 threads x 16B = full 64x64 bf16 tile in ONE issue per matrix.
  auto STAGE = [&](int it, int bsel) {
    int kv0 = it*64;
    const short* sk = qkv + (size_t)(b*SS + kv0 + (t >> 3))*ld + DIM + h*HD + srcCol;
    gload16(sk, &ldsK[bsel][wid*512]);
    const short* sv = vt + ((size_t)z*HD + (t >> 3))*SS + kv0 + srcCol;
    gload16(sv, &ldsV[bsel][wid*512]);
  };

  STAGE(0, 0);
  __syncthreads();
  for (int it = 0; it < ntiles; ++it) {
    int cur = it & 1;
    if (it + 1 < ntiles) STAGE(it + 1, cur ^ 1);
    int kv0 = it*64;
    if (it <= 2*qi + half) {           // wave-uniform activity predicate
      f32x4 sacc[4];
#pragma unroll
      for (int n = 0; n < 4; n++) sacc[n] = z4;
      __builtin_amdgcn_s_setprio(1);
#pragma unroll
      for (int n = 0; n < 4; n++) {
#pragma unroll
        for (int kk = 0; kk < 2; kk++) {
          int colK = (kk*32 + (lane >> 4)*8) ^ rowXor;
          short8 kb = *(const short8*)&ldsK[cur][(n*16 + (lane & 15))*64 + colK];
          sacc[n] = __builtin_amdgcn_mfma_f32_16x16x32_bf16(qf[kk], kb, sacc[n], 0, 0, 0);
        }
      }
      __builtin_amdgcn_s_setprio(0);
      if (it == 2*qi + half) {         // diagonal tile: mask raw scores
#pragma unroll
        for (int n = 0; n < 4; n++) {
          int kg = kv0 + n*16 + (lane & 15);
#pragma unroll
          for (int r = 0; r < 4; r++) {
            int qg = myq + ((lane >> 4) << 2) + r;
            sacc[n][r] = (kg <= qg) ? sacc[n][r] : -1e30f;
          }
        }
      }
      float mxs[4];
      float dmax = -1e30f;
#pragma unroll
      for (int r = 0; r < 4; r++) {
        float mx = fmaxf(fmaxf(sacc[0][r], sacc[1][r]), fmaxf(sacc[2][r], sacc[3][r]));
#pragma unroll
        for (int off = 1; off < 16; off <<= 1) mx = fmaxf(mx, __shfl_xor(mx, off));
        mxs[r] = mx * SCALE2;                       // scale once per row
        dmax = fmaxf(dmax, mxs[r] - m_r[r]);
      }
      if (__any(dmax > THR2)) {                     // T13: rescale only when needed
#pragma unroll
        for (int r = 0; r < 4; r++) {
          float mn = fmaxf(m_r[r], mxs[r]);
          float al = exp2f(m_r[r] - mn);
          m_r[r] = mn;
          lp[r] *= al;
#pragma unroll
          for (int n = 0; n < 4; n++) accO[n][r] *= al;
        }
      }
#pragma unroll
      for (int r = 0; r < 4; r++) {
        float mn = m_r[r];
        float rs = 0.f;
#pragma unroll
        for (int n = 0; n < 4; n++) {
          float p = exp2f(fmaf(sacc[n][r], SCALE2, -mn));
          sacc[n][r] = p;
          rs += p;
        }
        lp[r] += rs;                                // per-lane partial; reduce at end
      }
      // P -> per-wave LDS (A-operand layout, XOR-swizzled; same-wave r/w: no barrier)
#pragma unroll
      for (int n = 0; n < 4; n++)
#pragma unroll
        for (int r = 0; r < 4; r++) {
          int prow = ((lane >> 4) << 2) + r;
          int pcol = (n*16 + (lane & 15)) ^ ((prow & 7) << 3);
          ldsP[wid][prow*64 + pcol] = f2b(sacc[n][r]);
        }
      __builtin_amdgcn_s_setprio(1);
#pragma unroll
      for (int nn = 0; nn < 4; nn++) {
#pragma unroll
        for (int kk = 0; kk < 2; kk++) {
          int colP = (kk*32 + (lane >> 4)*8) ^ rowXor;
          short8 vb  = *(const short8*)&ldsV[cur][(nn*16 + (lane & 15))*64 + colP];
          short8 pfr = *(const short8*)&ldsP[wid][(lane & 15)*64 + colP];
          accO[nn] = __builtin_amdgcn_mfma_f32_16x16x32_bf16(pfr, vb, accO[nn], 0, 0, 0);
        }
      }
      __builtin_amdgcn_s_setprio(0);
    }
    __syncthreads();   // next tile staged; all waves done with cur bufs
  }
  // epilogue: finish deferred l row-reduction, divide, store
  {
    float rl[4];
#pragma unroll
    for (int r = 0; r < 4; r++) {
      float l = lp[r];
#pragma unroll
      for (int off = 1; off < 16; off <<= 1) l += __shfl_xor(l, off);
      rl[r] = 1.0f / l;
    }
#pragma unroll
    for (int nn = 0; nn < 4; nn++) {
#pragma unroll
      for (int r = 0; r < 4; r++) {
        int qg = myq + ((lane >> 4) << 2) + r;
        float ov = accO[nn][r] * rl[r];
        qkv[(size_t)(b*SS + qg)*ld + 2*DIM + h*HD + nn*16 + (lane & 15)] = f2b(ov);
      }
    }
  }
}

extern "C" void kernel_launch(void* const* d_in, const int* in_sizes, int n_in,
                              void* d_out, int out_size, void* d_ws, size_t ws_size,
                              hipStream_t stream) {
  (void)in_sizes; (void)n_in; (void)out_size; (void)ws_size;
  const float* x    = (const float*)d_in[0];
  // d_in[1] = mask: causal with -1e9 fill -> applied analytically, ignored
  const float* wq   = (const float*)d_in[2];
  const float* wk   = (const float*)d_in[3];
  const float* wv   = (const float*)d_in[4];
  const float* wo   = (const float*)d_in[5];
  const float* w1   = (const float*)d_in[6];
  const float* w2   = (const float*)d_in[7];
  const float* ln1w = (const float*)d_in[8];
  const float* ln1b = (const float*)d_in[9];
  const float* ln2w = (const float*)d_in[10];
  const float* ln2b = (const float*)d_in[11];
  float* out = (float*)d_out;   // fp32 output (verified r8)

  short* ws = (short*)d_ws;
  size_t o = 0;
  short* wqkvT = ws + o; o += (size_t)3*DIM*DIM;   // [3072][1024] bf16
  short* woT   = ws + o; o += (size_t)DIM*DIM;     // [1024][1024]
  short* w1T   = ws + o; o += (size_t)HID*DIM;     // [4096][1024]
  short* w2T   = ws + o; o += (size_t)DIM*HID;     // [1024][4096]
  short* xn    = ws + o; o += (size_t)NROW*DIM;    // LN1 out -> LN2 out (disjoint lifetimes)
  short* qkv   = ws + o; o += (size_t)NROW*3*DIM;  // q|k|v cols; v cols overwritten by attn out
  short* ff1   = ws + o; o += (size_t)NROW*HID;    // relu(hn@w1); front 16MB doubles as vt earlier
  short* vtb   = ff1;                              // [b,h,d,s] — lifetime disjoint from ff1

  dim3 B256(256), B512(512);
  // weight transposes (fp32 -> bf16, B^T convention): 4 square mats in ONE launch
  transp_f2b4<<<dim3(16,16,4), B256, 0, stream>>>(wq, wk, wv, wo,
                                                  wqkvT, wqkvT + DIM*DIM, wqkvT + 2*DIM*DIM, woT);
  transp_f2b<<<dim3(16,64), B256, 0, stream>>>(w1, w1T, DIM, HID);
  transp_f2b<<<dim3(64,16), B256, 0, stream>>>(w2, w2T, HID, DIM);
  // xn = LN1(x)   (fp32 in, bf16 out)
  ln_k<<<NROW, B256, 0, stream>>>(x, ln1w, ln1b, xn);
  // qkv = xn @ [wq|wk|wv]   (bf16 out)
  gemm_bt<0, short><<<dim3(NROW/128, 3*DIM/128), B512, 0, stream>>>(xn, DIM, wqkvT, DIM, qkv, 3*DIM, nullptr, 0, DIM);
  // vt = transpose(v) per (b,h)
  vtrans<<<dim3(SS/64, BB*NH), B256, 0, stream>>>(qkv, vtb);
  // attention (writes into qkv v-columns, bf16)
  attn_k<<<dim3(1024), B512, 0, stream>>>(qkv, vtb);
  // h = x + attn @ wo   (fp32 h in d_out)
  gemm_bt<3, float><<<dim3(NROW/128, DIM/128), B512, 0, stream>>>(qkv + 2*DIM, 3*DIM, woT, DIM, out, DIM, x, DIM, DIM);
  // hn = LN2(h) (fp32 in, bf16 out into xn)
  ln_k<<<NROW, B256, 0, stream>>>(out, ln2w, ln2b, xn);
  // ff1 = relu(hn @ w1)  (bf16 out)
  gemm_bt<1, short><<<dim3(NROW/128, HID/128), B512, 0, stream>>>(xn, DIM, w1T, DIM, ff1, HID, nullptr, 0, DIM);
  // out = h + ff1 @ w2   (fp32 in-place residual: each element read+written by its own thread)
  gemm_bt<3, float><<<dim3(NROW/128, DIM/128), B512, 0, stream>>>(ff1, HID, w2T, HID, out, DIM, out, DIM, HID);
}

// Round 21
// 384.991 us; speedup vs baseline: 1.1765x; 1.0086x over previous
//
#include <hip/hip_runtime.h>
#include <hip/hip_bf16.h>
#include <type_traits>

#define DIM 1024
#define HID 4096
#define NH 16
#define HD 64
#define BB 4
#define SS 2048
#define NROW (BB*SS)   // 8192

typedef __attribute__((ext_vector_type(8))) short short8;
typedef __attribute__((ext_vector_type(4))) short short4v;
typedef __attribute__((ext_vector_type(4))) float f32x4;

__device__ __forceinline__ void gload16(const void* src, void* lds) {
  __builtin_amdgcn_global_load_lds(
      (const __attribute__((address_space(1))) unsigned int*)src,
      (__attribute__((address_space(3))) unsigned int*)lds, 16, 0, 0);
}
__device__ __forceinline__ short f2b(float f) {
  return __builtin_bit_cast(short, __float2bfloat16(f));
}
__device__ __forceinline__ float b2f(short s) {
  return __uint_as_float(((unsigned)(unsigned short)s) << 16);
}

// ---------------- LayerNorm: one row (1024) per 256-thread block ----------------
// fp32 in, bf16 out.
__global__ __launch_bounds__(256) void ln_k(const float* __restrict__ x,
                                            const float* __restrict__ g,
                                            const float* __restrict__ bta,
                                            short* __restrict__ out) {
  int row = blockIdx.x;
  int t = threadIdx.x;
  int lane = t & 63, wid = t >> 6;
  float4 v = *(const float4*)(x + (size_t)row*DIM + t*4);
  float f[4] = {v.x, v.y, v.z, v.w};
  float s1 = 0.f, s2 = 0.f;
#pragma unroll
  for (int j = 0; j < 4; j++) { s1 += f[j]; s2 += f[j]*f[j]; }
#pragma unroll
  for (int off = 32; off > 0; off >>= 1) { s1 += __shfl_xor(s1, off); s2 += __shfl_xor(s2, off); }
  __shared__ float red[8];
  if (lane == 0) { red[wid] = s1; red[4+wid] = s2; }
  __syncthreads();
  s1 = red[0]+red[1]+red[2]+red[3];
  s2 = red[4]+red[5]+red[6]+red[7];
  float mu = s1 * (1.0f/DIM);
  float var = s2 * (1.0f/DIM) - mu*mu;
  float rs = rsqrtf(var + 1e-5f);
  float4 gv = *(const float4*)(g + t*4);
  float4 bv = *(const float4*)(bta + t*4);
  short4v o;
  o[0] = f2b((f[0]-mu)*rs*gv.x + bv.x);
  o[1] = f2b((f[1]-mu)*rs*gv.y + bv.y);
  o[2] = f2b((f[2]-mu)*rs*gv.z + bv.z);
  o[3] = f2b((f[3]-mu)*rs*gv.w + bv.w);
  *(short4v*)(out + (size_t)row*DIM + t*4) = o;
}

// ------------- fp32 -> bf16 2D transpose (R,C multiples of 64) -------------
__global__ __launch_bounds__(256) void transp_f2b(const float* __restrict__ in, short* __restrict__ out,
                                                  int R, int C) {
  __shared__ __align__(16) short tile[64][72];
  int r0 = blockIdx.x*64, c0 = blockIdx.y*64;
  int t = threadIdx.x;
  int cr = t >> 4;           // 0..15
  int cc4 = (t & 15) * 4;    // 0..60
#pragma unroll
  for (int i = 0; i < 4; i++) {
    float4 v = *(const float4*)(in + (size_t)(r0 + cr + i*16)*C + c0 + cc4);
    tile[cr + i*16][cc4 + 0] = f2b(v.x);
    tile[cr + i*16][cc4 + 1] = f2b(v.y);
    tile[cr + i*16][cc4 + 2] = f2b(v.z);
    tile[cr + i*16][cc4 + 3] = f2b(v.w);
  }
  __syncthreads();
  int rr = t >> 3, cc = (t & 7) * 8;
#pragma unroll
  for (int i = 0; i < 2; i++) {
    int oc = rr + i*32;
    short8 v;
#pragma unroll
    for (int j = 0; j < 8; j++) v[j] = tile[cc + j][oc];
    *(short8*)(out + (size_t)(c0 + oc)*R + r0 + cc) = v;
  }
}

// ------------- batched 1024x1024 fp32 -> bf16 transpose (4 matrices, one launch) -------------
__global__ __launch_bounds__(256) void transp_f2b4(const float* __restrict__ w0, const float* __restrict__ w1,
                                                   const float* __restrict__ w2, const float* __restrict__ w3,
                                                   short* __restrict__ o0, short* __restrict__ o1,
                                                   short* __restrict__ o2, short* __restrict__ o3) {
  __shared__ __align__(16) short tile[64][72];
  int zz = blockIdx.z;
  const float* in = (zz == 0) ? w0 : (zz == 1) ? w1 : (zz == 2) ? w2 : w3;
  short* out = (zz == 0) ? o0 : (zz == 1) ? o1 : (zz == 2) ? o2 : o3;
  const int R = DIM, C = DIM;
  int r0 = blockIdx.x*64, c0 = blockIdx.y*64;
  int t = threadIdx.x;
  int cr = t >> 4;
  int cc4 = (t & 15) * 4;
#pragma unroll
  for (int i = 0; i < 4; i++) {
    float4 v = *(const float4*)(in + (size_t)(r0 + cr + i*16)*C + c0 + cc4);
    tile[cr + i*16][cc4 + 0] = f2b(v.x);
    tile[cr + i*16][cc4 + 1] = f2b(v.y);
    tile[cr + i*16][cc4 + 2] = f2b(v.z);
    tile[cr + i*16][cc4 + 3] = f2b(v.w);
  }
  __syncthreads();
  int rr = t >> 3, cc = (t & 7) * 8;
#pragma unroll
  for (int i = 0; i < 2; i++) {
    int oc = rr + i*32;
    short8 v;
#pragma unroll
    for (int j = 0; j < 8; j++) v[j] = tile[cc + j][oc];
    *(short8*)(out + (size_t)(c0 + oc)*R + r0 + cc) = v;
  }
}

// ---------------- V transpose: qkv v-cols [b,s,h,d] -> vt [b,h,d,s] ----------------
__global__ __launch_bounds__(256) void vtrans(const short* __restrict__ qkv, short* __restrict__ vt) {
  __shared__ __align__(16) short tile[64][72];
  int s0 = blockIdx.x*64;
  int z = blockIdx.y; int b = z >> 4, h = z & 15;
  int t = threadIdx.x;
  int rr = t >> 3, cc = (t & 7) * 8;
#pragma unroll
  for (int i = 0; i < 2; i++) {
    short8 v = *(const short8*)(qkv + (size_t)(b*SS + s0 + rr + i*32)*(3*DIM) + 2*DIM + h*HD + cc);
    *(short8*)&tile[rr + i*32][cc] = v;
  }
  __syncthreads();
#pragma unroll
  for (int i = 0; i < 2; i++) {
    int d = rr + i*32;
    short8 v;
#pragma unroll
    for (int j = 0; j < 8; j++) v[j] = tile[cc + j][d];
    *(short8*)(vt + ((size_t)z*HD + d)*SS + s0 + cc) = v;
  }
}

// ---------------- GEMM: C[M,N] = A[M,K] * Bt[N,K]^T  (128² tile, BK=128, 8 waves) ----------------
// r18/r20 measured-best version. 512 threads, 2Mx4N waves, 64x32/wave.
// BK=128: minimal barrier-drain events at zero occupancy cost (VGPR-capped 2 blocks/CU).
// [128][128] bf16 LDS rows (256B) -> 16-slot XOR swizzle (rule #21).
// EPI: 0 = none, 1 = relu, 3 = add fp32 residual.  CT: short (bf16 out) or float (fp32 out).
template<int EPI, typename CT>
__global__ __launch_bounds__(512) void gemm_bt(const short* __restrict__ A, int lda,
                                               const short* __restrict__ Bt, int ldb,
                                               CT* C, int ldc,
                                               const float* Res, int ldr,
                                               int K) {
  __shared__ __align__(16) short ldsA[128*128];   // 32 KB
  __shared__ __align__(16) short ldsB[128*128];   // 32 KB
  int t = threadIdx.x, lane = t & 63, wid = t >> 6;
  int bm = blockIdx.x*128, bn = blockIdx.y*128;
  int wr = wid >> 2, wc = wid & 3;     // 2M x 4N wave grid, 64x32 per wave
  f32x4 z4 = {0.f, 0.f, 0.f, 0.f};
  f32x4 acc[4][2];
#pragma unroll
  for (int m = 0; m < 4; m++)
#pragma unroll
    for (int n = 0; n < 2; n++) acc[m][n] = z4;
  const int srcCol = (((t & 15) ^ ((t >> 4) & 15)) * 8);
  const short* pa = A + (size_t)(bm + (t >> 4))*lda + srcCol;
  const short* pb = Bt + (size_t)(bn + (t >> 4))*ldb + srcCol;
  const int rdXor = (lane & 15) << 3;   // read-side col XOR (frag row&15 == lane&15)
  for (int k0 = 0; k0 < K; k0 += 128) {
#pragma unroll
    for (int i = 0; i < 4; i++) {
      gload16(pa + (size_t)(i*32)*lda, &ldsA[i*4096 + wid*512]);
      gload16(pb + (size_t)(i*32)*ldb, &ldsB[i*4096 + wid*512]);
    }
    pa += 128; pb += 128;
    __syncthreads();
#pragma unroll
    for (int kk = 0; kk < 4; kk++) {
      short8 af[4], bfr[2];
#pragma unroll
      for (int m = 0; m < 4; m++) {
        int row = wr*64 + m*16 + (lane & 15);
        af[m] = *(const short8*)&ldsA[row*128 + ((kk*32 + (lane >> 4)*8) ^ rdXor)];
      }
#pragma unroll
      for (int n = 0; n < 2; n++) {
        int row = wc*32 + n*16 + (lane & 15);
        bfr[n] = *(const short8*)&ldsB[row*128 + ((kk*32 + (lane >> 4)*8) ^ rdXor)];
      }
#pragma unroll
      for (int m = 0; m < 4; m++)
#pragma unroll
        for (int n = 0; n < 2; n++)
          acc[m][n] = __builtin_amdgcn_mfma_f32_16x16x32_bf16(af[m], bfr[n], acc[m][n], 0, 0, 0);
    }
    __syncthreads();
  }
#pragma unroll
  for (int m = 0; m < 4; m++) {
    int r0 = bm + wr*64 + m*16 + ((lane >> 4) << 2);
#pragma unroll
    for (int n = 0; n < 2; n++) {
      int c = bn + wc*32 + n*16 + (lane & 15);
#pragma unroll
      for (int r = 0; r < 4; r++) {
        float v = acc[m][n][r];
        if constexpr (EPI == 1) v = fmaxf(v, 0.0f);
        if constexpr (EPI == 3) v += Res[(size_t)(r0 + r)*ldr + c];
        if constexpr (std::is_same<CT, float>::value)
          C[(size_t)(r0 + r)*ldc + c] = v;
        else
          C[(size_t)(r0 + r)*ldc + c] = f2b(v);
      }
    }
  }
}

// ---------------- causal flash attention (MFMA, paired q-tiles, 8 waves) ----------------
// 512 blocks; block (z, p) processes q-tiles {15-p, p} back-to-back -> EXACTLY 34 KV-tiles
// per block (uniform), 2 blocks/CU, zero tail. Flat 34-iteration virtual-tile loop keeps the
// double-buffer prefetch chain continuous across the phase boundary (block-uniform switch:
// epilogue-A, state reset, Q reload). Compute body identical to the r20 measured version.
__global__ __launch_bounds__(512) void attn_k(short* qkv, const short* __restrict__ vt) {
  __shared__ __align__(16) short ldsK[2][64*64];
  __shared__ __align__(16) short ldsV[2][64*64];
  __shared__ __align__(16) short ldsP[8][16*64];
  int t = threadIdx.x, lane = t & 63, wid = t >> 6;
  int wgid = blockIdx.x;
  int xcd = wgid & 7, idx = wgid >> 3;
  int z  = xcd*8 + (idx & 7);          // all 8 blocks of a z stay on one XCD
  int p  = idx >> 3;                   // pair index 0..7
  int qiA = 15 - p, qiB = p;           // long phase first
  int b = z >> 4, h = z & 15;
  const int ld = 3*DIM;
  const float SCALE2 = 0.125f * 1.44269504f;   // 1/sqrt(HD) * log2(e)
  const float THR2   = 8.0f * 1.44269504f;     // defer-max threshold (exp2 domain)
  const int half = wid >> 2;
  const int nA = 2*qiA + 2;
  const int NT = 34;                   // nA + nB == 34 for every pair

  short8 qf[2];
  f32x4 z4 = {0.f, 0.f, 0.f, 0.f};
  f32x4 accO[4];
  float m_r[4], lp[4];
  const int srcCol = (((lane & 7) ^ ((lane >> 3) & 7)) * 8);  // pre-swizzled staging col
  const int rowXor = (lane & 7) << 3;                         // read-side col XOR

  auto LOADQ = [&](int q0) {
    const short* qp = qkv + (size_t)(b*SS + q0 + wid*16 + (lane & 15))*ld + h*HD + (lane >> 4)*8;
    qf[0] = *(const short8*)qp;
    qf[1] = *(const short8*)(qp + 32);
  };
  auto RESET = [&]() {
#pragma unroll
    for (int n = 0; n < 4; n++) accO[n] = z4;
#pragma unroll
    for (int r = 0; r < 4; r++) { m_r[r] = -1e30f; lp[r] = 0.f; }
  };
  auto EPILOG = [&](int q0e) {
    float rl[4];
#pragma unroll
    for (int r = 0; r < 4; r++) {
      float l = lp[r];
#pragma unroll
      for (int off = 1; off < 16; off <<= 1) l += __shfl_xor(l, off);
      rl[r] = 1.0f / l;
    }
#pragma unroll
    for (int nn = 0; nn < 4; nn++)
#pragma unroll
      for (int r = 0; r < 4; r++) {
        int qg = q0e + wid*16 + ((lane >> 4) << 2) + r;
        qkv[(size_t)(b*SS + qg)*ld + 2*DIM + h*HD + nn*16 + (lane & 15)] = f2b(accO[nn][r] * rl[r]);
      }
  };
  // 512 threads x 16B = full 64x64 bf16 tile in ONE issue per matrix.
  auto STAGE = [&](int kv0, int bsel) {
    const short* sk = qkv + (size_t)(b*SS + kv0 + (t >> 3))*ld + DIM + h*HD + srcCol;
    gload16(sk, &ldsK[bsel][wid*512]);
    const short* sv = vt + ((size_t)z*HD + (t >> 3))*SS + kv0 + srcCol;
    gload16(sv, &ldsV[bsel][wid*512]);
  };

  LOADQ(qiA*128);
  RESET();
  int qi = qiA, q0 = qiA*128;
  STAGE(0, 0);
  __syncthreads();
  for (int v = 0; v < NT; ++v) {
    int cur = v & 1;
    if (v + 1 < NT) {
      int vn = v + 1;
      STAGE(((vn >= nA) ? vn - nA : vn) * 64, cur ^ 1);
    }
    if (v == nA) {                     // phase switch (block-uniform)
      EPILOG(q0);
      RESET();
      qi = qiB; q0 = qiB*128;
      LOADQ(q0);
    }
    int it = (v >= nA) ? v - nA : v;
    int kv0 = it*64;
    if (it <= 2*qi + half) {           // wave-uniform activity predicate
      f32x4 sacc[4];
#pragma unroll
      for (int n = 0; n < 4; n++) sacc[n] = z4;
      __builtin_amdgcn_s_setprio(1);
#pragma unroll
      for (int n = 0; n < 4; n++) {
#pragma unroll
        for (int kk = 0; kk < 2; kk++) {
          int colK = (kk*32 + (lane >> 4)*8) ^ rowXor;
          short8 kb = *(const short8*)&ldsK[cur][(n*16 + (lane & 15))*64 + colK];
          sacc[n] = __builtin_amdgcn_mfma_f32_16x16x32_bf16(qf[kk], kb, sacc[n], 0, 0, 0);
        }
      }
      __builtin_amdgcn_s_setprio(0);
      if (it == 2*qi + half) {         // diagonal tile: mask raw scores
#pragma unroll
        for (int n = 0; n < 4; n++) {
          int kg = kv0 + n*16 + (lane & 15);
#pragma unroll
          for (int r = 0; r < 4; r++) {
            int qg = q0 + wid*16 + ((lane >> 4) << 2) + r;
            sacc[n][r] = (kg <= qg) ? sacc[n][r] : -1e30f;
          }
        }
      }
      float mxs[4];
      float dmax = -1e30f;
#pragma unroll
      for (int r = 0; r < 4; r++) {
        float mx = fmaxf(fmaxf(sacc[0][r], sacc[1][r]), fmaxf(sacc[2][r], sacc[3][r]));
#pragma unroll
        for (int off = 1; off < 16; off <<= 1) mx = fmaxf(mx, __shfl_xor(mx, off));
        mxs[r] = mx * SCALE2;                       // scale once per row
        dmax = fmaxf(dmax, mxs[r] - m_r[r]);
      }
      if (__any(dmax > THR2)) {                     // T13: rescale only when needed
#pragma unroll
        for (int r = 0; r < 4; r++) {
          float mn = fmaxf(m_r[r], mxs[r]);
          float al = exp2f(m_r[r] - mn);
          m_r[r] = mn;
          lp[r] *= al;
#pragma unroll
          for (int n = 0; n < 4; n++) accO[n][r] *= al;
        }
      }
#pragma unroll
      for (int r = 0; r < 4; r++) {
        float mn = m_r[r];
        float rs = 0.f;
#pragma unroll
        for (int n = 0; n < 4; n++) {
          float p2 = exp2f(fmaf(sacc[n][r], SCALE2, -mn));
          sacc[n][r] = p2;
          rs += p2;
        }
        lp[r] += rs;                                // per-lane partial; reduce at end
      }
      // P -> per-wave LDS (A-operand layout, XOR-swizzled; same-wave r/w: no barrier)
#pragma unroll
      for (int n = 0; n < 4; n++)
#pragma unroll
        for (int r = 0; r < 4; r++) {
          int prow = ((lane >> 4) << 2) + r;
          int pcol = (n*16 + (lane & 15)) ^ ((prow & 7) << 3);
          ldsP[wid][prow*64 + pcol] = f2b(sacc[n][r]);
        }
      __builtin_amdgcn_s_setprio(1);
#pragma unroll
      for (int nn = 0; nn < 4; nn++) {
#pragma unroll
        for (int kk = 0; kk < 2; kk++) {
          int colP = (kk*32 + (lane >> 4)*8) ^ rowXor;
          short8 vb  = *(const short8*)&ldsV[cur][(nn*16 + (lane & 15))*64 + colP];
          short8 pfr = *(const short8*)&ldsP[wid][(lane & 15)*64 + colP];
          accO[nn] = __builtin_amdgcn_mfma_f32_16x16x32_bf16(pfr, vb, accO[nn], 0, 0, 0);
        }
      }
      __builtin_amdgcn_s_setprio(0);
    }
    __syncthreads();   // next tile staged; all waves done with cur bufs
  }
  EPILOG(q0);          // phase B epilogue
}

extern "C" void kernel_launch(void* const* d_in, const int* in_sizes, int n_in,
                              void* d_out, int out_size, void* d_ws, size_t ws_size,
                              hipStream_t stream) {
  (void)in_sizes; (void)n_in; (void)out_size; (void)ws_size;
  const float* x    = (const float*)d_in[0];
  // d_in[1] = mask: causal with -1e9 fill -> applied analytically, ignored
  const float* wq   = (const float*)d_in[2];
  const float* wk   = (const float*)d_in[3];
  const float* wv   = (const float*)d_in[4];
  const float* wo   = (const float*)d_in[5];
  const float* w1   = (const float*)d_in[6];
  const float* w2   = (const float*)d_in[7];
  const float* ln1w = (const float*)d_in[8];
  const float* ln1b = (const float*)d_in[9];
  const float* ln2w = (const float*)d_in[10];
  const float* ln2b = (const float*)d_in[11];
  float* out = (float*)d_out;   // fp32 output (verified r8)

  short* ws = (short*)d_ws;
  size_t o = 0;
  short* wqkvT = ws + o; o += (size_t)3*DIM*DIM;   // [3072][1024] bf16
  short* woT   = ws + o; o += (size_t)DIM*DIM;     // [1024][1024]
  short* w1T   = ws + o; o += (size_t)HID*DIM;     // [4096][1024]
  short* w2T   = ws + o; o += (size_t)DIM*HID;     // [1024][4096]
  short* xn    = ws + o; o += (size_t)NROW*DIM;    // LN1 out -> LN2 out (disjoint lifetimes)
  short* qkv   = ws + o; o += (size_t)NROW*3*DIM;  // q|k|v cols; v cols overwritten by attn out
  short* ff1   = ws + o; o += (size_t)NROW*HID;    // relu(hn@w1); front 16MB doubles as vt earlier
  short* vtb   = ff1;                              // [b,h,d,s] — lifetime disjoint from ff1

  dim3 B256(256), B512(512);
  // weight transposes (fp32 -> bf16, B^T convention): 4 square mats in ONE launch
  transp_f2b4<<<dim3(16,16,4), B256, 0, stream>>>(wq, wk, wv, wo,
                                                  wqkvT, wqkvT + DIM*DIM, wqkvT + 2*DIM*DIM, woT);
  transp_f2b<<<dim3(16,64), B256, 0, stream>>>(w1, w1T, DIM, HID);
  transp_f2b<<<dim3(64,16), B256, 0, stream>>>(w2, w2T, HID, DIM);
  // xn = LN1(x)   (fp32 in, bf16 out)
  ln_k<<<NROW, B256, 0, stream>>>(x, ln1w, ln1b, xn);
  // qkv = xn @ [wq|wk|wv]   (bf16 out)
  gemm_bt<0, short><<<dim3(NROW/128, 3*DIM/128), B512, 0, stream>>>(xn, DIM, wqkvT, DIM, qkv, 3*DIM, nullptr, 0, DIM);
  // vt = transpose(v) per (b,h)
  vtrans<<<dim3(SS/64, BB*NH), B256, 0, stream>>>(qkv, vtb);
  // attention (paired q-tiles; writes into qkv v-columns, bf16)
  attn_k<<<dim3(512), B512, 0, stream>>>(qkv, vtb);
  // h = x + attn @ wo   (fp32 h in d_out)
  gemm_bt<3, float><<<dim3(NROW/128, DIM/128), B512, 0, stream>>>(qkv + 2*DIM, 3*DIM, woT, DIM, out, DIM, x, DIM, DIM);
  // hn = LN2(h) (fp32 in, bf16 out into xn)
  ln_k<<<NROW, B256, 0, stream>>>(out, ln2w, ln2b, xn);
  // ff1 = relu(hn @ w1)  (bf16 out)
  gemm_bt<1, short><<<dim3(NROW/128, HID/128), B512, 0, stream>>>(xn, DIM, w1T, DIM, ff1, HID, nullptr, 0, DIM);
  // out = h + ff1 @ w2   (fp32 in-place residual: each element read+written by its own thread)
  gemm_bt<3, float><<<dim3(NROW/128, DIM/128), B512, 0, stream>>>(ff1, HID, w2T, HID, out, DIM, out, DIM, HID);
}

// Round 22
// 380.494 us; speedup vs baseline: 1.1904x; 1.0118x over previous
//
#include <hip/hip_runtime.h>
#include <hip/hip_bf16.h>
#include <type_traits>

#define DIM 1024
#define HID 4096
#define NH 16
#define HD 64
#define BB 4
#define SS 2048
#define NROW (BB*SS)   // 8192

typedef __attribute__((ext_vector_type(8))) short short8;
typedef __attribute__((ext_vector_type(4))) short short4v;
typedef __attribute__((ext_vector_type(4))) float f32x4;

__device__ __forceinline__ void gload16(const void* src, void* lds) {
  __builtin_amdgcn_global_load_lds(
      (const __attribute__((address_space(1))) unsigned int*)src,
      (__attribute__((address_space(3))) unsigned int*)lds, 16, 0, 0);
}
__device__ __forceinline__ short f2b(float f) {
  return __builtin_bit_cast(short, __float2bfloat16(f));
}
__device__ __forceinline__ float b2f(short s) {
  return __uint_as_float(((unsigned)(unsigned short)s) << 16);
}

// ---------------- LayerNorm: one row (1024) per 256-thread block ----------------
// fp32 in, bf16 out.
__global__ __launch_bounds__(256) void ln_k(const float* __restrict__ x,
                                            const float* __restrict__ g,
                                            const float* __restrict__ bta,
                                            short* __restrict__ out) {
  int row = blockIdx.x;
  int t = threadIdx.x;
  int lane = t & 63, wid = t >> 6;
  float4 v = *(const float4*)(x + (size_t)row*DIM + t*4);
  float f[4] = {v.x, v.y, v.z, v.w};
  float s1 = 0.f, s2 = 0.f;
#pragma unroll
  for (int j = 0; j < 4; j++) { s1 += f[j]; s2 += f[j]*f[j]; }
#pragma unroll
  for (int off = 32; off > 0; off >>= 1) { s1 += __shfl_xor(s1, off); s2 += __shfl_xor(s2, off); }
  __shared__ float red[8];
  if (lane == 0) { red[wid] = s1; red[4+wid] = s2; }
  __syncthreads();
  s1 = red[0]+red[1]+red[2]+red[3];
  s2 = red[4]+red[5]+red[6]+red[7];
  float mu = s1 * (1.0f/DIM);
  float var = s2 * (1.0f/DIM) - mu*mu;
  float rs = rsqrtf(var + 1e-5f);
  float4 gv = *(const float4*)(g + t*4);
  float4 bv = *(const float4*)(bta + t*4);
  short4v o;
  o[0] = f2b((f[0]-mu)*rs*gv.x + bv.x);
  o[1] = f2b((f[1]-mu)*rs*gv.y + bv.y);
  o[2] = f2b((f[2]-mu)*rs*gv.z + bv.z);
  o[3] = f2b((f[3]-mu)*rs*gv.w + bv.w);
  *(short4v*)(out + (size_t)row*DIM + t*4) = o;
}

// ------------- fp32 -> bf16 2D transpose (R,C multiples of 64) -------------
__global__ __launch_bounds__(256) void transp_f2b(const float* __restrict__ in, short* __restrict__ out,
                                                  int R, int C) {
  __shared__ __align__(16) short tile[64][72];
  int r0 = blockIdx.x*64, c0 = blockIdx.y*64;
  int t = threadIdx.x;
  int cr = t >> 4;           // 0..15
  int cc4 = (t & 15) * 4;    // 0..60
#pragma unroll
  for (int i = 0; i < 4; i++) {
    float4 v = *(const float4*)(in + (size_t)(r0 + cr + i*16)*C + c0 + cc4);
    tile[cr + i*16][cc4 + 0] = f2b(v.x);
    tile[cr + i*16][cc4 + 1] = f2b(v.y);
    tile[cr + i*16][cc4 + 2] = f2b(v.z);
    tile[cr + i*16][cc4 + 3] = f2b(v.w);
  }
  __syncthreads();
  int rr = t >> 3, cc = (t & 7) * 8;
#pragma unroll
  for (int i = 0; i < 2; i++) {
    int oc = rr + i*32;
    short8 v;
#pragma unroll
    for (int j = 0; j < 8; j++) v[j] = tile[cc + j][oc];
    *(short8*)(out + (size_t)(c0 + oc)*R + r0 + cc) = v;
  }
}

// ------------- batched 1024x1024 fp32 -> bf16 transpose (4 matrices, one launch) -------------
__global__ __launch_bounds__(256) void transp_f2b4(const float* __restrict__ w0, const float* __restrict__ w1,
                                                   const float* __restrict__ w2, const float* __restrict__ w3,
                                                   short* __restrict__ o0, short* __restrict__ o1,
                                                   short* __restrict__ o2, short* __restrict__ o3) {
  __shared__ __align__(16) short tile[64][72];
  int zz = blockIdx.z;
  const float* in = (zz == 0) ? w0 : (zz == 1) ? w1 : (zz == 2) ? w2 : w3;
  short* out = (zz == 0) ? o0 : (zz == 1) ? o1 : (zz == 2) ? o2 : o3;
  const int R = DIM, C = DIM;
  int r0 = blockIdx.x*64, c0 = blockIdx.y*64;
  int t = threadIdx.x;
  int cr = t >> 4;
  int cc4 = (t & 15) * 4;
#pragma unroll
  for (int i = 0; i < 4; i++) {
    float4 v = *(const float4*)(in + (size_t)(r0 + cr + i*16)*C + c0 + cc4);
    tile[cr + i*16][cc4 + 0] = f2b(v.x);
    tile[cr + i*16][cc4 + 1] = f2b(v.y);
    tile[cr + i*16][cc4 + 2] = f2b(v.z);
    tile[cr + i*16][cc4 + 3] = f2b(v.w);
  }
  __syncthreads();
  int rr = t >> 3, cc = (t & 7) * 8;
#pragma unroll
  for (int i = 0; i < 2; i++) {
    int oc = rr + i*32;
    short8 v;
#pragma unroll
    for (int j = 0; j < 8; j++) v[j] = tile[cc + j][oc];
    *(short8*)(out + (size_t)(c0 + oc)*R + r0 + cc) = v;
  }
}

// ---------------- V transpose: qkv v-cols [b,s,h,d] -> vt [b,h,d,s] ----------------
__global__ __launch_bounds__(256) void vtrans(const short* __restrict__ qkv, short* __restrict__ vt) {
  __shared__ __align__(16) short tile[64][72];
  int s0 = blockIdx.x*64;
  int z = blockIdx.y; int b = z >> 4, h = z & 15;
  int t = threadIdx.x;
  int rr = t >> 3, cc = (t & 7) * 8;
#pragma unroll
  for (int i = 0; i < 2; i++) {
    short8 v = *(const short8*)(qkv + (size_t)(b*SS + s0 + rr + i*32)*(3*DIM) + 2*DIM + h*HD + cc);
    *(short8*)&tile[rr + i*32][cc] = v;
  }
  __syncthreads();
#pragma unroll
  for (int i = 0; i < 2; i++) {
    int d = rr + i*32;
    short8 v;
#pragma unroll
    for (int j = 0; j < 8; j++) v[j] = tile[cc + j][d];
    *(short8*)(vt + ((size_t)z*HD + d)*SS + s0 + cc) = v;
  }
}

// ---------------- GEMM: C[M,N] = A[M,K] * Bt[N,K]^T  (128² tile, BK=128, 8 waves) ----------------
// r18/r20 measured-best version. 512 threads, 2Mx4N waves, 64x32/wave.
// EPI: 0 = none, 1 = relu, 3 = add fp32 residual.  CT: short (bf16 out) or float (fp32 out).
template<int EPI, typename CT>
__global__ __launch_bounds__(512) void gemm_bt(const short* __restrict__ A, int lda,
                                               const short* __restrict__ Bt, int ldb,
                                               CT* C, int ldc,
                                               const float* Res, int ldr,
                                               int K) {
  __shared__ __align__(16) short ldsA[128*128];   // 32 KB
  __shared__ __align__(16) short ldsB[128*128];   // 32 KB
  int t = threadIdx.x, lane = t & 63, wid = t >> 6;
  int bm = blockIdx.x*128, bn = blockIdx.y*128;
  int wr = wid >> 2, wc = wid & 3;     // 2M x 4N wave grid, 64x32 per wave
  f32x4 z4 = {0.f, 0.f, 0.f, 0.f};
  f32x4 acc[4][2];
#pragma unroll
  for (int m = 0; m < 4; m++)
#pragma unroll
    for (int n = 0; n < 2; n++) acc[m][n] = z4;
  const int srcCol = (((t & 15) ^ ((t >> 4) & 15)) * 8);
  const short* pa = A + (size_t)(bm + (t >> 4))*lda + srcCol;
  const short* pb = Bt + (size_t)(bn + (t >> 4))*ldb + srcCol;
  const int rdXor = (lane & 15) << 3;   // read-side col XOR (frag row&15 == lane&15)
  for (int k0 = 0; k0 < K; k0 += 128) {
#pragma unroll
    for (int i = 0; i < 4; i++) {
      gload16(pa + (size_t)(i*32)*lda, &ldsA[i*4096 + wid*512]);
      gload16(pb + (size_t)(i*32)*ldb, &ldsB[i*4096 + wid*512]);
    }
    pa += 128; pb += 128;
    __syncthreads();
#pragma unroll
    for (int kk = 0; kk < 4; kk++) {
      short8 af[4], bfr[2];
#pragma unroll
      for (int m = 0; m < 4; m++) {
        int row = wr*64 + m*16 + (lane & 15);
        af[m] = *(const short8*)&ldsA[row*128 + ((kk*32 + (lane >> 4)*8) ^ rdXor)];
      }
#pragma unroll
      for (int n = 0; n < 2; n++) {
        int row = wc*32 + n*16 + (lane & 15);
        bfr[n] = *(const short8*)&ldsB[row*128 + ((kk*32 + (lane >> 4)*8) ^ rdXor)];
      }
#pragma unroll
      for (int m = 0; m < 4; m++)
#pragma unroll
        for (int n = 0; n < 2; n++)
          acc[m][n] = __builtin_amdgcn_mfma_f32_16x16x32_bf16(af[m], bfr[n], acc[m][n], 0, 0, 0);
    }
    __syncthreads();
  }
#pragma unroll
  for (int m = 0; m < 4; m++) {
    int r0 = bm + wr*64 + m*16 + ((lane >> 4) << 2);
#pragma unroll
    for (int n = 0; n < 2; n++) {
      int c = bn + wc*32 + n*16 + (lane & 15);
#pragma unroll
      for (int r = 0; r < 4; r++) {
        float v = acc[m][n][r];
        if constexpr (EPI == 1) v = fmaxf(v, 0.0f);
        if constexpr (EPI == 3) v += Res[(size_t)(r0 + r)*ldr + c];
        if constexpr (std::is_same<CT, float>::value)
          C[(size_t)(r0 + r)*ldc + c] = v;
        else
          C[(size_t)(r0 + r)*ldc + c] = f2b(v);
      }
    }
  }
}

// ---------------- causal flash attention (MFMA, KVBLK=128, paired q-tiles, 8 waves) ----------------
// 512 blocks; block (z, p) processes q-tiles {15-p, p} -> EXACTLY 17 KV-tiles of 128 (uniform).
// Halved barrier count vs KVBLK=64. K tile [128 s][64 d] (8-slot XOR swizzle);
// V tile [64 d][128 s] (16-slot XOR swizzle, same scheme as the BK=128 GEMM).
// Diagonal tile: wave w skips fully-masked frags n>w (wave-uniform); n==w per-element mask.
// PV runs in two 64-col halves through the per-wave 16x64 P buffer (same-wave hazard
// ordered by compiler lgkm waits). LDS 80KB -> 2 blocks/CU.
__global__ __launch_bounds__(512) void attn_k(short* qkv, const short* __restrict__ vt) {
  __shared__ __align__(16) short ldsK[2][128*64];
  __shared__ __align__(16) short ldsV[2][64*128];
  __shared__ __align__(16) short ldsP[8][16*64];
  int t = threadIdx.x, lane = t & 63, wid = t >> 6;
  int wgid = blockIdx.x;
  int xcd = wgid & 7, idx = wgid >> 3;
  int z  = xcd*8 + (idx & 7);          // all 8 blocks of a z stay on one XCD
  int p  = idx >> 3;                   // pair index 0..7
  int qiA = 15 - p, qiB = p;           // long phase first
  int b = z >> 4, h = z & 15;
  const int ld = 3*DIM;
  const float SCALE2 = 0.125f * 1.44269504f;   // 1/sqrt(HD) * log2(e)
  const float THR2   = 8.0f * 1.44269504f;     // defer-max threshold (exp2 domain)
  const int nA = qiA + 1;
  const int NT = 17;                   // (qiA+1)+(qiB+1) uniform

  short8 qf[2];
  f32x4 z4 = {0.f, 0.f, 0.f, 0.f};
  f32x4 accO[4];
  float m_r[4], lp[4];
  const int srcColK = (((t & 7) ^ ((t >> 3) & 7)) * 8);    // 8-slot swizzle (64-wide rows)
  const int srcColV = (((t & 15) ^ ((t >> 4) & 15)) * 8);  // 16-slot swizzle (128-wide rows)
  const int rowXor8  = (lane & 7) << 3;
  const int rowXor16 = (lane & 15) << 3;

  auto LOADQ = [&](int q0) {
    const short* qp = qkv + (size_t)(b*SS + q0 + wid*16 + (lane & 15))*ld + h*HD + (lane >> 4)*8;
    qf[0] = *(const short8*)qp;
    qf[1] = *(const short8*)(qp + 32);
  };
  auto RESET = [&]() {
#pragma unroll
    for (int n = 0; n < 4; n++) accO[n] = z4;
#pragma unroll
    for (int r = 0; r < 4; r++) { m_r[r] = -1e30f; lp[r] = 0.f; }
  };
  auto EPILOG = [&](int q0e) {
    float rl[4];
#pragma unroll
    for (int r = 0; r < 4; r++) {
      float l = lp[r];
#pragma unroll
      for (int off = 1; off < 16; off <<= 1) l += __shfl_xor(l, off);
      rl[r] = 1.0f / l;
    }
#pragma unroll
    for (int nn = 0; nn < 4; nn++)
#pragma unroll
      for (int r = 0; r < 4; r++) {
        int qg = q0e + wid*16 + ((lane >> 4) << 2) + r;
        qkv[(size_t)(b*SS + qg)*ld + 2*DIM + h*HD + nn*16 + (lane & 15)] = f2b(accO[nn][r] * rl[r]);
      }
  };
  // K: 2 issues (rows 0-63, 64-127); V: 2 issues (d rows 0-31, 32-63). Dest lane-linear.
  auto STAGE = [&](int kv0, int bsel) {
    const short* sk = qkv + (size_t)(b*SS + kv0 + (t >> 3))*ld + DIM + h*HD + srcColK;
    gload16(sk,                 &ldsK[bsel][wid*512]);
    gload16(sk + (size_t)64*ld, &ldsK[bsel][4096 + wid*512]);
    const short* sv = vt + ((size_t)z*HD + (t >> 4))*SS + kv0 + srcColV;
    gload16(sv,                 &ldsV[bsel][wid*512]);
    gload16(sv + (size_t)32*SS, &ldsV[bsel][4096 + wid*512]);
  };

  LOADQ(qiA*128);
  RESET();
  int qi = qiA, q0 = qiA*128;
  STAGE(0, 0);
  __syncthreads();
  for (int v = 0; v < NT; ++v) {
    int cur = v & 1;
    if (v + 1 < NT) {
      int vn = v + 1;
      STAGE(((vn >= nA) ? vn - nA : vn) * 128, cur ^ 1);
    }
    if (v == nA) {                     // phase switch (block-uniform)
      EPILOG(q0);
      RESET();
      qi = qiB; q0 = qiB*128;
      LOADQ(q0);
    }
    int it = (v >= nA) ? v - nA : v;
    int kv0 = it*128;
    bool diag = (it == qi);
    f32x4 sacc[8];
#pragma unroll
    for (int n = 0; n < 8; n++) sacc[n] = z4;
    // QK^T over 128 kv cols (8 frags); on diag skip fully-masked frags (n > wid)
    __builtin_amdgcn_s_setprio(1);
#pragma unroll
    for (int n = 0; n < 8; n++) {
      if (!diag || n <= wid) {
#pragma unroll
        for (int kk = 0; kk < 2; kk++) {
          int colK = (kk*32 + (lane >> 4)*8) ^ rowXor8;
          short8 kb = *(const short8*)&ldsK[cur][(n*16 + (lane & 15))*64 + colK];
          sacc[n] = __builtin_amdgcn_mfma_f32_16x16x32_bf16(qf[kk], kb, sacc[n], 0, 0, 0);
        }
      }
    }
    __builtin_amdgcn_s_setprio(0);
    if (diag) {
#pragma unroll
      for (int n = 0; n < 8; n++) {
        if (n == wid) {                // triangular frag: per-element mask
          int kg = kv0 + n*16 + (lane & 15);
#pragma unroll
          for (int r = 0; r < 4; r++) {
            int qg = q0 + wid*16 + ((lane >> 4) << 2) + r;
            sacc[n][r] = (kg <= qg) ? sacc[n][r] : -1e30f;
          }
        } else if (n > wid) {          // fully masked
#pragma unroll
          for (int r = 0; r < 4; r++) sacc[n][r] = -1e30f;
        }
      }
    }
    // softmax over 8 frags (exp2 domain; raw-domain max)
    float mxs[4];
    float dmax = -1e30f;
#pragma unroll
    for (int r = 0; r < 4; r++) {
      float m01 = fmaxf(sacc[0][r], sacc[1][r]);
      float m23 = fmaxf(sacc[2][r], sacc[3][r]);
      float m45 = fmaxf(sacc[4][r], sacc[5][r]);
      float m67 = fmaxf(sacc[6][r], sacc[7][r]);
      float mx = fmaxf(fmaxf(m01, m23), fmaxf(m45, m67));
#pragma unroll
      for (int off = 1; off < 16; off <<= 1) mx = fmaxf(mx, __shfl_xor(mx, off));
      mxs[r] = mx * SCALE2;
      dmax = fmaxf(dmax, mxs[r] - m_r[r]);
    }
    if (__any(dmax > THR2)) {          // T13: rescale only when needed
#pragma unroll
      for (int r = 0; r < 4; r++) {
        float mn = fmaxf(m_r[r], mxs[r]);
        float al = exp2f(m_r[r] - mn);
        m_r[r] = mn;
        lp[r] *= al;
#pragma unroll
        for (int n = 0; n < 4; n++) accO[n][r] *= al;
      }
    }
#pragma unroll
    for (int r = 0; r < 4; r++) {
      float mn = m_r[r];
      float rs = 0.f;
#pragma unroll
      for (int n = 0; n < 8; n++) {
        float p2 = exp2f(fmaf(sacc[n][r], SCALE2, -mn));
        sacc[n][r] = p2;
        rs += p2;
      }
      lp[r] += rs;                     // per-lane partial; reduce at epilogue
    }
    // PV in two 64-col halves through the per-wave P buffer
#pragma unroll
    for (int hh = 0; hh < 2; hh++) {
#pragma unroll
      for (int j = 0; j < 4; j++)
#pragma unroll
        for (int r = 0; r < 4; r++) {
          int prow = ((lane >> 4) << 2) + r;
          int pcol = (j*16 + (lane & 15)) ^ ((prow & 7) << 3);
          ldsP[wid][prow*64 + pcol] = f2b(sacc[hh*4 + j][r]);
        }
      __builtin_amdgcn_s_setprio(1);
#pragma unroll
      for (int nn = 0; nn < 4; nn++) {
#pragma unroll
        for (int kk2 = 0; kk2 < 2; kk2++) {
          int colP = (kk2*32 + (lane >> 4)*8) ^ rowXor8;
          short8 pfr = *(const short8*)&ldsP[wid][(lane & 15)*64 + colP];
          int colV = ((hh*2 + kk2)*32 + (lane >> 4)*8) ^ rowXor16;
          short8 vb = *(const short8*)&ldsV[cur][(nn*16 + (lane & 15))*128 + colV];
          accO[nn] = __builtin_amdgcn_mfma_f32_16x16x32_bf16(pfr, vb, accO[nn], 0, 0, 0);
        }
      }
      __builtin_amdgcn_s_setprio(0);
    }
    __syncthreads();   // next tile staged; all waves done with cur bufs
  }
  EPILOG(q0);          // phase B epilogue
}

extern "C" void kernel_launch(void* const* d_in, const int* in_sizes, int n_in,
                              void* d_out, int out_size, void* d_ws, size_t ws_size,
                              hipStream_t stream) {
  (void)in_sizes; (void)n_in; (void)out_size; (void)ws_size;
  const float* x    = (const float*)d_in[0];
  // d_in[1] = mask: causal with -1e9 fill -> applied analytically, ignored
  const float* wq   = (const float*)d_in[2];
  const float* wk   = (const float*)d_in[3];
  const float* wv   = (const float*)d_in[4];
  const float* wo   = (const float*)d_in[5];
  const float* w1   = (const float*)d_in[6];
  const float* w2   = (const float*)d_in[7];
  const float* ln1w = (const float*)d_in[8];
  const float* ln1b = (const float*)d_in[9];
  const float* ln2w = (const float*)d_in[10];
  const float* ln2b = (const float*)d_in[11];
  float* out = (float*)d_out;   // fp32 output (verified r8)

  short* ws = (short*)d_ws;
  size_t o = 0;
  short* wqkvT = ws + o; o += (size_t)3*DIM*DIM;   // [3072][1024] bf16
  short* woT   = ws + o; o += (size_t)DIM*DIM;     // [1024][1024]
  short* w1T   = ws + o; o += (size_t)HID*DIM;     // [4096][1024]
  short* w2T   = ws + o; o += (size_t)DIM*HID;     // [1024][4096]
  short* xn    = ws + o; o += (size_t)NROW*DIM;    // LN1 out -> LN2 out (disjoint lifetimes)
  short* qkv   = ws + o; o += (size_t)NROW*3*DIM;  // q|k|v cols; v cols overwritten by attn out
  short* ff1   = ws + o; o += (size_t)NROW*HID;    // relu(hn@w1); front 16MB doubles as vt earlier
  short* vtb   = ff1;                              // [b,h,d,s] — lifetime disjoint from ff1

  dim3 B256(256), B512(512);
  // weight transposes (fp32 -> bf16, B^T convention): 4 square mats in ONE launch
  transp_f2b4<<<dim3(16,16,4), B256, 0, stream>>>(wq, wk, wv, wo,
                                                  wqkvT, wqkvT + DIM*DIM, wqkvT + 2*DIM*DIM, woT);
  transp_f2b<<<dim3(16,64), B256, 0, stream>>>(w1, w1T, DIM, HID);
  transp_f2b<<<dim3(64,16), B256, 0, stream>>>(w2, w2T, HID, DIM);
  // xn = LN1(x)   (fp32 in, bf16 out)
  ln_k<<<NROW, B256, 0, stream>>>(x, ln1w, ln1b, xn);
  // qkv = xn @ [wq|wk|wv]   (bf16 out)
  gemm_bt<0, short><<<dim3(NROW/128, 3*DIM/128), B512, 0, stream>>>(xn, DIM, wqkvT, DIM, qkv, 3*DIM, nullptr, 0, DIM);
  // vt = transpose(v) per (b,h)
  vtrans<<<dim3(SS/64, BB*NH), B256, 0, stream>>>(qkv, vtb);
  // attention (KVBLK=128, paired q-tiles; writes into qkv v-columns, bf16)
  attn_k<<<dim3(512), B512, 0, stream>>>(qkv, vtb);
  // h = x + attn @ wo   (fp32 h in d_out)
  gemm_bt<3, float><<<dim3(NROW/128, DIM/128), B512, 0, stream>>>(qkv + 2*DIM, 3*DIM, woT, DIM, out, DIM, x, DIM, DIM);
  // hn = LN2(h) (fp32 in, bf16 out into xn)
  ln_k<<<NROW, B256, 0, stream>>>(out, ln2w, ln2b, xn);
  // ff1 = relu(hn @ w1)  (bf16 out)
  gemm_bt<1, short><<<dim3(NROW/128, HID/128), B512, 0, stream>>>(xn, DIM, w1T, DIM, ff1, HID, nullptr, 0, DIM);
  // out = h + ff1 @ w2   (fp32 in-place residual: each element read+written by its own thread)
  gemm_bt<3, float><<<dim3(NROW/128, DIM/128), B512, 0, stream>>>(ff1, HID, w2T, HID, out, DIM, out, DIM, HID);
}

// Round 23
// 375.690 us; speedup vs baseline: 1.2056x; 1.0128x over previous
//
#include <hip/hip_runtime.h>
#include <hip/hip_bf16.h>
#include <type_traits>

#define DIM 1024
#define HID 4096
#define NH 16
#define HD 64
#define BB 4
#define SS 2048
#define NROW (BB*SS)   // 8192

typedef __attribute__((ext_vector_type(8))) short short8;
typedef __attribute__((ext_vector_type(4))) short short4v;
typedef __attribute__((ext_vector_type(4))) float f32x4;

__device__ __forceinline__ void gload16(const void* src, void* lds) {
  __builtin_amdgcn_global_load_lds(
      (const __attribute__((address_space(1))) unsigned int*)src,
      (__attribute__((address_space(3))) unsigned int*)lds, 16, 0, 0);
}
__device__ __forceinline__ short f2b(float f) {
  return __builtin_bit_cast(short, __float2bfloat16(f));
}
__device__ __forceinline__ float b2f(short s) {
  return __uint_as_float(((unsigned)(unsigned short)s) << 16);
}

// ---------------- LayerNorm: one row (1024) per 256-thread block ----------------
// fp32 in, bf16 out.
__global__ __launch_bounds__(256) void ln_k(const float* __restrict__ x,
                                            const float* __restrict__ g,
                                            const float* __restrict__ bta,
                                            short* __restrict__ out) {
  int row = blockIdx.x;
  int t = threadIdx.x;
  int lane = t & 63, wid = t >> 6;
  float4 v = *(const float4*)(x + (size_t)row*DIM + t*4);
  float f[4] = {v.x, v.y, v.z, v.w};
  float s1 = 0.f, s2 = 0.f;
#pragma unroll
  for (int j = 0; j < 4; j++) { s1 += f[j]; s2 += f[j]*f[j]; }
#pragma unroll
  for (int off = 32; off > 0; off >>= 1) { s1 += __shfl_xor(s1, off); s2 += __shfl_xor(s2, off); }
  __shared__ float red[8];
  if (lane == 0) { red[wid] = s1; red[4+wid] = s2; }
  __syncthreads();
  s1 = red[0]+red[1]+red[2]+red[3];
  s2 = red[4]+red[5]+red[6]+red[7];
  float mu = s1 * (1.0f/DIM);
  float var = s2 * (1.0f/DIM) - mu*mu;
  float rs = rsqrtf(var + 1e-5f);
  float4 gv = *(const float4*)(g + t*4);
  float4 bv = *(const float4*)(bta + t*4);
  short4v o;
  o[0] = f2b((f[0]-mu)*rs*gv.x + bv.x);
  o[1] = f2b((f[1]-mu)*rs*gv.y + bv.y);
  o[2] = f2b((f[2]-mu)*rs*gv.z + bv.z);
  o[3] = f2b((f[3]-mu)*rs*gv.w + bv.w);
  *(short4v*)(out + (size_t)row*DIM + t*4) = o;
}

// ------------- fp32 -> bf16 2D transpose (R,C multiples of 64) -------------
__global__ __launch_bounds__(256) void transp_f2b(const float* __restrict__ in, short* __restrict__ out,
                                                  int R, int C) {
  __shared__ __align__(16) short tile[64][72];
  int r0 = blockIdx.x*64, c0 = blockIdx.y*64;
  int t = threadIdx.x;
  int cr = t >> 4;           // 0..15
  int cc4 = (t & 15) * 4;    // 0..60
#pragma unroll
  for (int i = 0; i < 4; i++) {
    float4 v = *(const float4*)(in + (size_t)(r0 + cr + i*16)*C + c0 + cc4);
    tile[cr + i*16][cc4 + 0] = f2b(v.x);
    tile[cr + i*16][cc4 + 1] = f2b(v.y);
    tile[cr + i*16][cc4 + 2] = f2b(v.z);
    tile[cr + i*16][cc4 + 3] = f2b(v.w);
  }
  __syncthreads();
  int rr = t >> 3, cc = (t & 7) * 8;
#pragma unroll
  for (int i = 0; i < 2; i++) {
    int oc = rr + i*32;
    short8 v;
#pragma unroll
    for (int j = 0; j < 8; j++) v[j] = tile[cc + j][oc];
    *(short8*)(out + (size_t)(c0 + oc)*R + r0 + cc) = v;
  }
}

// ------------- batched 1024x1024 fp32 -> bf16 transpose (4 matrices, one launch) -------------
__global__ __launch_bounds__(256) void transp_f2b4(const float* __restrict__ w0, const float* __restrict__ w1,
                                                   const float* __restrict__ w2, const float* __restrict__ w3,
                                                   short* __restrict__ o0, short* __restrict__ o1,
                                                   short* __restrict__ o2, short* __restrict__ o3) {
  __shared__ __align__(16) short tile[64][72];
  int zz = blockIdx.z;
  const float* in = (zz == 0) ? w0 : (zz == 1) ? w1 : (zz == 2) ? w2 : w3;
  short* out = (zz == 0) ? o0 : (zz == 1) ? o1 : (zz == 2) ? o2 : o3;
  const int R = DIM, C = DIM;
  int r0 = blockIdx.x*64, c0 = blockIdx.y*64;
  int t = threadIdx.x;
  int cr = t >> 4;
  int cc4 = (t & 15) * 4;
#pragma unroll
  for (int i = 0; i < 4; i++) {
    float4 v = *(const float4*)(in + (size_t)(r0 + cr + i*16)*C + c0 + cc4);
    tile[cr + i*16][cc4 + 0] = f2b(v.x);
    tile[cr + i*16][cc4 + 1] = f2b(v.y);
    tile[cr + i*16][cc4 + 2] = f2b(v.z);
    tile[cr + i*16][cc4 + 3] = f2b(v.w);
  }
  __syncthreads();
  int rr = t >> 3, cc = (t & 7) * 8;
#pragma unroll
  for (int i = 0; i < 2; i++) {
    int oc = rr + i*32;
    short8 v;
#pragma unroll
    for (int j = 0; j < 8; j++) v[j] = tile[cc + j][oc];
    *(short8*)(out + (size_t)(c0 + oc)*R + r0 + cc) = v;
  }
}

// ---------------- GEMM: C[M,N] = A[M,K] * Bt[N,K]^T  (128² tile, BK=128, 8 waves) ----------------
// r18/r20 measured-best structure. 512 threads, 2Mx4N waves, 64x32/wave.
// EPI: 0 = none, 1 = relu, 3 = add fp32 residual,
//      4 = qkv mode: cols >= 2*DIM (the V columns) are written TRANSPOSED to vtx
//          in [b,h,d,s] layout (packed 4-s short4 stores) and NOT to C — fuses vtrans.
// CT: short (bf16 out) or float (fp32 out).
template<int EPI, typename CT>
__global__ __launch_bounds__(512) void gemm_bt(const short* __restrict__ A, int lda,
                                               const short* __restrict__ Bt, int ldb,
                                               CT* C, int ldc,
                                               const float* Res, int ldr,
                                               int K, short* vtx) {
  __shared__ __align__(16) short ldsA[128*128];   // 32 KB
  __shared__ __align__(16) short ldsB[128*128];   // 32 KB
  int t = threadIdx.x, lane = t & 63, wid = t >> 6;
  int bm = blockIdx.x*128, bn = blockIdx.y*128;
  int wr = wid >> 2, wc = wid & 3;     // 2M x 4N wave grid, 64x32 per wave
  f32x4 z4 = {0.f, 0.f, 0.f, 0.f};
  f32x4 acc[4][2];
#pragma unroll
  for (int m = 0; m < 4; m++)
#pragma unroll
    for (int n = 0; n < 2; n++) acc[m][n] = z4;
  const int srcCol = (((t & 15) ^ ((t >> 4) & 15)) * 8);
  const short* pa = A + (size_t)(bm + (t >> 4))*lda + srcCol;
  const short* pb = Bt + (size_t)(bn + (t >> 4))*ldb + srcCol;
  const int rdXor = (lane & 15) << 3;   // read-side col XOR (frag row&15 == lane&15)
  for (int k0 = 0; k0 < K; k0 += 128) {
#pragma unroll
    for (int i = 0; i < 4; i++) {
      gload16(pa + (size_t)(i*32)*lda, &ldsA[i*4096 + wid*512]);
      gload16(pb + (size_t)(i*32)*ldb, &ldsB[i*4096 + wid*512]);
    }
    pa += 128; pb += 128;
    __syncthreads();
#pragma unroll
    for (int kk = 0; kk < 4; kk++) {
      short8 af[4], bfr[2];
#pragma unroll
      for (int m = 0; m < 4; m++) {
        int row = wr*64 + m*16 + (lane & 15);
        af[m] = *(const short8*)&ldsA[row*128 + ((kk*32 + (lane >> 4)*8) ^ rdXor)];
      }
#pragma unroll
      for (int n = 0; n < 2; n++) {
        int row = wc*32 + n*16 + (lane & 15);
        bfr[n] = *(const short8*)&ldsB[row*128 + ((kk*32 + (lane >> 4)*8) ^ rdXor)];
      }
#pragma unroll
      for (int m = 0; m < 4; m++)
#pragma unroll
        for (int n = 0; n < 2; n++)
          acc[m][n] = __builtin_amdgcn_mfma_f32_16x16x32_bf16(af[m], bfr[n], acc[m][n], 0, 0, 0);
    }
    __syncthreads();
  }
#pragma unroll
  for (int m = 0; m < 4; m++) {
    int r0 = bm + wr*64 + m*16 + ((lane >> 4) << 2);
#pragma unroll
    for (int n = 0; n < 2; n++) {
      int c = bn + wc*32 + n*16 + (lane & 15);
      if constexpr (EPI == 4) {
        if (c >= 2*DIM) {              // V columns -> vtx [b,h,d,s], packed 4 consecutive s
          int hd = c - 2*DIM;          // h*64 + d
          int bq = r0 >> 11;           // batch (SS = 2048)
          int s  = r0 & 2047;
          short4v o;
#pragma unroll
          for (int r = 0; r < 4; r++) o[r] = f2b(acc[m][n][r]);
          *(short4v*)(vtx + ((size_t)(bq*NH*HD) + hd)*SS + s) = o;
          continue;
        }
      }
#pragma unroll
      for (int r = 0; r < 4; r++) {
        float v = acc[m][n][r];
        if constexpr (EPI == 1) v = fmaxf(v, 0.0f);
        if constexpr (EPI == 3) v += Res[(size_t)(r0 + r)*ldr + c];
        if constexpr (std::is_same<CT, float>::value)
          C[(size_t)(r0 + r)*ldc + c] = v;
        else
          C[(size_t)(r0 + r)*ldc + c] = f2b(v);
      }
    }
  }
}

// ---------------- causal flash attention (MFMA, KVBLK=128, paired q-tiles, 8 waves) ----------------
// 512 blocks; block (z, p) processes q-tiles {15-p, p} -> EXACTLY 17 KV-tiles of 128 (uniform).
// K tile [128 s][64 d] (8-slot XOR swizzle); V tile [64 d][128 s] (16-slot XOR swizzle).
// Diagonal tile: wave w skips fully-masked frags n>w; n==w per-element mask.
// PV in two 64-col halves through the per-wave 16x64 P buffer. LDS 80KB -> 2 blocks/CU.
__global__ __launch_bounds__(512) void attn_k(short* qkv, const short* __restrict__ vt) {
  __shared__ __align__(16) short ldsK[2][128*64];
  __shared__ __align__(16) short ldsV[2][64*128];
  __shared__ __align__(16) short ldsP[8][16*64];
  int t = threadIdx.x, lane = t & 63, wid = t >> 6;
  int wgid = blockIdx.x;
  int xcd = wgid & 7, idx = wgid >> 3;
  int z  = xcd*8 + (idx & 7);          // all 8 blocks of a z stay on one XCD
  int p  = idx >> 3;                   // pair index 0..7
  int qiA = 15 - p, qiB = p;           // long phase first
  int b = z >> 4, h = z & 15;
  const int ld = 3*DIM;
  const float SCALE2 = 0.125f * 1.44269504f;   // 1/sqrt(HD) * log2(e)
  const float THR2   = 8.0f * 1.44269504f;     // defer-max threshold (exp2 domain)
  const int nA = qiA + 1;
  const int NT = 17;                   // (qiA+1)+(qiB+1) uniform

  short8 qf[2];
  f32x4 z4 = {0.f, 0.f, 0.f, 0.f};
  f32x4 accO[4];
  float m_r[4], lp[4];
  const int srcColK = (((t & 7) ^ ((t >> 3) & 7)) * 8);    // 8-slot swizzle (64-wide rows)
  const int srcColV = (((t & 15) ^ ((t >> 4) & 15)) * 8);  // 16-slot swizzle (128-wide rows)
  const int rowXor8  = (lane & 7) << 3;
  const int rowXor16 = (lane & 15) << 3;

  auto LOADQ = [&](int q0) {
    const short* qp = qkv + (size_t)(b*SS + q0 + wid*16 + (lane & 15))*ld + h*HD + (lane >> 4)*8;
    qf[0] = *(const short8*)qp;
    qf[1] = *(const short8*)(qp + 32);
  };
  auto RESET = [&]() {
#pragma unroll
    for (int n = 0; n < 4; n++) accO[n] = z4;
#pragma unroll
    for (int r = 0; r < 4; r++) { m_r[r] = -1e30f; lp[r] = 0.f; }
  };
  auto EPILOG = [&](int q0e) {
    float rl[4];
#pragma unroll
    for (int r = 0; r < 4; r++) {
      float l = lp[r];
#pragma unroll
      for (int off = 1; off < 16; off <<= 1) l += __shfl_xor(l, off);
      rl[r] = 1.0f / l;
    }
#pragma unroll
    for (int nn = 0; nn < 4; nn++)
#pragma unroll
      for (int r = 0; r < 4; r++) {
        int qg = q0e + wid*16 + ((lane >> 4) << 2) + r;
        qkv[(size_t)(b*SS + qg)*ld + 2*DIM + h*HD + nn*16 + (lane & 15)] = f2b(accO[nn][r] * rl[r]);
      }
  };
  // K: 2 issues (rows 0-63, 64-127); V: 2 issues (d rows 0-31, 32-63). Dest lane-linear.
  auto STAGE = [&](int kv0, int bsel) {
    const short* sk = qkv + (size_t)(b*SS + kv0 + (t >> 3))*ld + DIM + h*HD + srcColK;
    gload16(sk,                 &ldsK[bsel][wid*512]);
    gload16(sk + (size_t)64*ld, &ldsK[bsel][4096 + wid*512]);
    const short* sv = vt + ((size_t)z*HD + (t >> 4))*SS + kv0 + srcColV;
    gload16(sv,                 &ldsV[bsel][wid*512]);
    gload16(sv + (size_t)32*SS, &ldsV[bsel][4096 + wid*512]);
  };

  LOADQ(qiA*128);
  RESET();
  int qi = qiA, q0 = qiA*128;
  STAGE(0, 0);
  __syncthreads();
  for (int v = 0; v < NT; ++v) {
    int cur = v & 1;
    if (v + 1 < NT) {
      int vn = v + 1;
      STAGE(((vn >= nA) ? vn - nA : vn) * 128, cur ^ 1);
    }
    if (v == nA) {                     // phase switch (block-uniform)
      EPILOG(q0);
      RESET();
      qi = qiB; q0 = qiB*128;
      LOADQ(q0);
    }
    int it = (v >= nA) ? v - nA : v;
    int kv0 = it*128;
    bool diag = (it == qi);
    f32x4 sacc[8];
#pragma unroll
    for (int n = 0; n < 8; n++) sacc[n] = z4;
    // QK^T over 128 kv cols (8 frags); on diag skip fully-masked frags (n > wid)
    __builtin_amdgcn_s_setprio(1);
#pragma unroll
    for (int n = 0; n < 8; n++) {
      if (!diag || n <= wid) {
#pragma unroll
        for (int kk = 0; kk < 2; kk++) {
          int colK = (kk*32 + (lane >> 4)*8) ^ rowXor8;
          short8 kb = *(const short8*)&ldsK[cur][(n*16 + (lane & 15))*64 + colK];
          sacc[n] = __builtin_amdgcn_mfma_f32_16x16x32_bf16(qf[kk], kb, sacc[n], 0, 0, 0);
        }
      }
    }
    __builtin_amdgcn_s_setprio(0);
    if (diag) {
#pragma unroll
      for (int n = 0; n < 8; n++) {
        if (n == wid) {                // triangular frag: per-element mask
          int kg = kv0 + n*16 + (lane & 15);
#pragma unroll
          for (int r = 0; r < 4; r++) {
            int qg = q0 + wid*16 + ((lane >> 4) << 2) + r;
            sacc[n][r] = (kg <= qg) ? sacc[n][r] : -1e30f;
          }
        } else if (n > wid) {          // fully masked
#pragma unroll
          for (int r = 0; r < 4; r++) sacc[n][r] = -1e30f;
        }
      }
    }
    // softmax over 8 frags (exp2 domain; raw-domain max)
    float mxs[4];
    float dmax = -1e30f;
#pragma unroll
    for (int r = 0; r < 4; r++) {
      float m01 = fmaxf(sacc[0][r], sacc[1][r]);
      float m23 = fmaxf(sacc[2][r], sacc[3][r]);
      float m45 = fmaxf(sacc[4][r], sacc[5][r]);
      float m67 = fmaxf(sacc[6][r], sacc[7][r]);
      float mx = fmaxf(fmaxf(m01, m23), fmaxf(m45, m67));
#pragma unroll
      for (int off = 1; off < 16; off <<= 1) mx = fmaxf(mx, __shfl_xor(mx, off));
      mxs[r] = mx * SCALE2;
      dmax = fmaxf(dmax, mxs[r] - m_r[r]);
    }
    if (__any(dmax > THR2)) {          // T13: rescale only when needed
#pragma unroll
      for (int r = 0; r < 4; r++) {
        float mn = fmaxf(m_r[r], mxs[r]);
        float al = exp2f(m_r[r] - mn);
        m_r[r] = mn;
        lp[r] *= al;
#pragma unroll
        for (int n = 0; n < 4; n++) accO[n][r] *= al;
      }
    }
#pragma unroll
    for (int r = 0; r < 4; r++) {
      float mn = m_r[r];
      float rs = 0.f;
#pragma unroll
      for (int n = 0; n < 8; n++) {
        float p2 = exp2f(fmaf(sacc[n][r], SCALE2, -mn));
        sacc[n][r] = p2;
        rs += p2;
      }
      lp[r] += rs;                     // per-lane partial; reduce at epilogue
    }
    // PV in two 64-col halves through the per-wave P buffer
#pragma unroll
    for (int hh = 0; hh < 2; hh++) {
#pragma unroll
      for (int j = 0; j < 4; j++)
#pragma unroll
        for (int r = 0; r < 4; r++) {
          int prow = ((lane >> 4) << 2) + r;
          int pcol = (j*16 + (lane & 15)) ^ ((prow & 7) << 3);
          ldsP[wid][prow*64 + pcol] = f2b(sacc[hh*4 + j][r]);
        }
      __builtin_amdgcn_s_setprio(1);
#pragma unroll
      for (int nn = 0; nn < 4; nn++) {
#pragma unroll
        for (int kk2 = 0; kk2 < 2; kk2++) {
          int colP = (kk2*32 + (lane >> 4)*8) ^ rowXor8;
          short8 pfr = *(const short8*)&ldsP[wid][(lane & 15)*64 + colP];
          int colV = ((hh*2 + kk2)*32 + (lane >> 4)*8) ^ rowXor16;
          short8 vb = *(const short8*)&ldsV[cur][(nn*16 + (lane & 15))*128 + colV];
          accO[nn] = __builtin_amdgcn_mfma_f32_16x16x32_bf16(pfr, vb, accO[nn], 0, 0, 0);
        }
      }
      __builtin_amdgcn_s_setprio(0);
    }
    __syncthreads();   // next tile staged; all waves done with cur bufs
  }
  EPILOG(q0);          // phase B epilogue
}

extern "C" void kernel_launch(void* const* d_in, const int* in_sizes, int n_in,
                              void* d_out, int out_size, void* d_ws, size_t ws_size,
                              hipStream_t stream) {
  (void)in_sizes; (void)n_in; (void)out_size; (void)ws_size;
  const float* x    = (const float*)d_in[0];
  // d_in[1] = mask: causal with -1e9 fill -> applied analytically, ignored
  const float* wq   = (const float*)d_in[2];
  const float* wk   = (const float*)d_in[3];
  const float* wv   = (const float*)d_in[4];
  const float* wo   = (const float*)d_in[5];
  const float* w1   = (const float*)d_in[6];
  const float* w2   = (const float*)d_in[7];
  const float* ln1w = (const float*)d_in[8];
  const float* ln1b = (const float*)d_in[9];
  const float* ln2w = (const float*)d_in[10];
  const float* ln2b = (const float*)d_in[11];
  float* out = (float*)d_out;   // fp32 output (verified r8)

  short* ws = (short*)d_ws;
  size_t o = 0;
  short* wqkvT = ws + o; o += (size_t)3*DIM*DIM;   // [3072][1024] bf16
  short* woT   = ws + o; o += (size_t)DIM*DIM;     // [1024][1024]
  short* w1T   = ws + o; o += (size_t)HID*DIM;     // [4096][1024]
  short* w2T   = ws + o; o += (size_t)DIM*HID;     // [1024][4096]
  short* xn    = ws + o; o += (size_t)NROW*DIM;    // LN1 out -> LN2 out (disjoint lifetimes)
  short* qkv   = ws + o; o += (size_t)NROW*3*DIM;  // q|k cols + attn-out in v cols
  short* ff1   = ws + o; o += (size_t)NROW*HID;    // relu(hn@w1); front 16MB doubles as vt earlier
  short* vtb   = ff1;                              // [b,h,d,s] — lifetime disjoint from ff1

  dim3 B256(256), B512(512);
  // weight transposes (fp32 -> bf16, B^T convention): 4 square mats in ONE launch
  transp_f2b4<<<dim3(16,16,4), B256, 0, stream>>>(wq, wk, wv, wo,
                                                  wqkvT, wqkvT + DIM*DIM, wqkvT + 2*DIM*DIM, woT);
  transp_f2b<<<dim3(16,64), B256, 0, stream>>>(w1, w1T, DIM, HID);
  transp_f2b<<<dim3(64,16), B256, 0, stream>>>(w2, w2T, HID, DIM);
  // xn = LN1(x)   (fp32 in, bf16 out)
  ln_k<<<NROW, B256, 0, stream>>>(x, ln1w, ln1b, xn);
  // qkv = xn @ [wq|wk|wv]; V columns land TRANSPOSED in vtb (fused vtrans, EPI=4)
  gemm_bt<4, short><<<dim3(NROW/128, 3*DIM/128), B512, 0, stream>>>(xn, DIM, wqkvT, DIM, qkv, 3*DIM, nullptr, 0, DIM, vtb);
  // attention (KVBLK=128, paired q-tiles; writes into qkv v-columns, bf16)
  attn_k<<<dim3(512), B512, 0, stream>>>(qkv, vtb);
  // h = x + attn @ wo   (fp32 h in d_out)
  gemm_bt<3, float><<<dim3(NROW/128, DIM/128), B512, 0, stream>>>(qkv + 2*DIM, 3*DIM, woT, DIM, out, DIM, x, DIM, DIM, nullptr);
  // hn = LN2(h) (fp32 in, bf16 out into xn)
  ln_k<<<NROW, B256, 0, stream>>>(out, ln2w, ln2b, xn);
  // ff1 = relu(hn @ w1)  (bf16 out)
  gemm_bt<1, short><<<dim3(NROW/128, HID/128), B512, 0, stream>>>(xn, DIM, w1T, DIM, ff1, HID, nullptr, 0, DIM, nullptr);
  // out = h + ff1 @ w2   (fp32 in-place residual: each element read+written by its own thread)
  gemm_bt<3, float><<<dim3(NROW/128, DIM/128), B512, 0, stream>>>(ff1, HID, w2T, HID, out, DIM, out, DIM, HID, nullptr);
}